// Round 16
// baseline (464.575 us; speedup 1.0000x reference)
//
#include <hip/hip_runtime.h>
#include <hip/hip_bf16.h>
#include <stdint.h>

#define DEVI __device__ __forceinline__

typedef __attribute__((ext_vector_type(4))) float f32x4;
typedef __attribute__((ext_vector_type(8))) short short8;
typedef __attribute__((ext_vector_type(4))) short s16x4;

constexpr int B_ = 2, S_ = 2048, D_ = 1024, E_ = 8, F_ = 2048;
constexpr int M_ = B_ * S_;        // 4096 tokens
constexpr int PC_ = 10240;         // padded pair capacity (8192 + 8*256)
constexpr int NC_ = 64, L_ = 32;   // scan chunking: NC_*L_ == S_
constexpr int HB_ = 16;            // hist blocks (HB_*512 == 2*M_)
constexpr size_t MD_ = (size_t)M_ * D_;
constexpr size_t DD_ = (size_t)D_ * D_;

DEVI short f2bf(float f) {
  uint32_t u = __float_as_uint(f);
  u = (u + 0x7fffu + ((u >> 16) & 1u)) >> 16;
  return (short)u;
}
DEVI float bf2f(short s) { return __uint_as_float(((uint32_t)(uint16_t)s) << 16); }
struct BfPair { short hi, lo; };
DEVI BfPair split2(float f) {
  BfPair p;
  p.hi = f2bf(f);
  p.lo = f2bf(f - bf2f(p.hi));
  return p;
}

DEVI void gload_lds16(const void* g, void* l) {
  __builtin_amdgcn_global_load_lds(
      (const __attribute__((address_space(1))) unsigned int*)g,
      (__attribute__((address_space(3))) unsigned int*)l, 16, 0, 0);
}

// bank-conflict swizzle: 16B-slot XOR within a 64B row (involution; applied
// to the global SOURCE slot at stage time and to the READ slot — LDS dest
// stays linear as required by global_load_lds).
DEVI int swz(int row, int slot) { return slot ^ ((row >> 1) & 3); }

#define MFMA(a, b, c) __builtin_amdgcn_mfma_f32_16x16x32_bf16((a), (b), (c), 0, 0, 0)

// ---- fused LN1 + time-mix ----
__global__ __launch_bounds__(256) void lnmix_kernel(
    const float* __restrict__ x, const float* __restrict__ g,
    const float* __restrict__ b, const float* __restrict__ muk,
    const float* __restrict__ muv, const float* __restrict__ mur,
    short* __restrict__ xk, short* __restrict__ xv, short* __restrict__ xr) {
  int row = blockIdx.x;
  int tx = threadIdx.x;
  int s = row & (S_ - 1);
  size_t o = (size_t)row * D_ + tx * 4;
  f32x4 cur = *(const f32x4*)(x + o);
  f32x4 prv = {0.f, 0.f, 0.f, 0.f};
  if (s > 0) prv = *(const f32x4*)(x + o - D_);
  float a0 = cur[0] + cur[1] + cur[2] + cur[3];
  float a1 = cur[0] * cur[0] + cur[1] * cur[1] + cur[2] * cur[2] + cur[3] * cur[3];
  float a2 = prv[0] + prv[1] + prv[2] + prv[3];
  float a3 = prv[0] * prv[0] + prv[1] * prv[1] + prv[2] * prv[2] + prv[3] * prv[3];
#pragma unroll
  for (int o2 = 32; o2; o2 >>= 1) {
    a0 += __shfl_down(a0, o2);
    a1 += __shfl_down(a1, o2);
    a2 += __shfl_down(a2, o2);
    a3 += __shfl_down(a3, o2);
  }
  __shared__ float rd[4][4];
  if ((tx & 63) == 0) {
    rd[tx >> 6][0] = a0; rd[tx >> 6][1] = a1;
    rd[tx >> 6][2] = a2; rd[tx >> 6][3] = a3;
  }
  __syncthreads();
  a0 = rd[0][0] + rd[1][0] + rd[2][0] + rd[3][0];
  a1 = rd[0][1] + rd[1][1] + rd[2][1] + rd[3][1];
  a2 = rd[0][2] + rd[1][2] + rd[2][2] + rd[3][2];
  a3 = rd[0][3] + rd[1][3] + rd[2][3] + rd[3][3];
  float mc = a0 * (1.0f / D_);
  float rc = rsqrtf(a1 * (1.0f / D_) - mc * mc + 1e-5f);
  float mp = a2 * (1.0f / D_);
  float rp = rsqrtf(a3 * (1.0f / D_) - mp * mp + 1e-5f);
  int d = tx * 4;
  f32x4 gg = *(const f32x4*)(g + d);
  f32x4 bb = *(const f32x4*)(b + d);
  f32x4 mk = *(const f32x4*)(muk + d);
  f32x4 mv = *(const f32x4*)(muv + d);
  f32x4 mr = *(const f32x4*)(mur + d);
  s16x4 okh, okl, ovh, ovl, orh, orl;
#pragma unroll
  for (int j = 0; j < 4; j++) {
    float c = (cur[j] - mc) * rc * gg[j] + bb[j];
    float p = (s > 0) ? (prv[j] - mp) * rp * gg[j] + bb[j] : 0.f;
    BfPair pk = split2(c * mk[j] + p * (1.f - mk[j]));
    BfPair pv = split2(c * mv[j] + p * (1.f - mv[j]));
    BfPair pr = split2(c * mr[j] + p * (1.f - mr[j]));
    okh[j] = pk.hi; okl[j] = pk.lo;
    ovh[j] = pv.hi; ovl[j] = pv.lo;
    orh[j] = pr.hi; orl[j] = pr.lo;
  }
  *(s16x4*)(xk + o) = okh;
  *(s16x4*)(xk + MD_ + o) = okl;
  *(s16x4*)(xv + o) = ovh;
  *(s16x4*)(xv + MD_ + o) = ovl;
  *(s16x4*)(xr + o) = orh;
  *(s16x4*)(xr + MD_ + o) = orl;
}

// ---- fused: xout = x + P0+P1; ei = LN(xout); router logits+top2 (NO atomics)
__global__ __launch_bounds__(256) void ln2_router(
    const float* __restrict__ x, const float* __restrict__ P,
    const float* __restrict__ g, const float* __restrict__ b,
    const float* __restrict__ rw, float* __restrict__ xout,
    float* __restrict__ ei, int* __restrict__ idx2, float* __restrict__ wts2) {
  int row = blockIdx.x;
  int tx = threadIdx.x;
  size_t o = (size_t)row * D_ + tx * 4;
  f32x4 v = *(const f32x4*)(x + o);
  f32x4 p0 = *(const f32x4*)(P + o);
  f32x4 p1 = *(const f32x4*)(P + MD_ + o);
#pragma unroll
  for (int j = 0; j < 4; j++) v[j] += p0[j] + p1[j];
  *(f32x4*)(xout + o) = v;
  float s = v[0] + v[1] + v[2] + v[3];
  float s2 = v[0] * v[0] + v[1] * v[1] + v[2] * v[2] + v[3] * v[3];
#pragma unroll
  for (int of = 32; of; of >>= 1) {
    s += __shfl_down(s, of);
    s2 += __shfl_down(s2, of);
  }
  __shared__ float w1[4], w2[4];
  if ((tx & 63) == 0) { w1[tx >> 6] = s; w2[tx >> 6] = s2; }
  __syncthreads();
  s = w1[0] + w1[1] + w1[2] + w1[3];
  s2 = w2[0] + w2[1] + w2[2] + w2[3];
  float mean = s * (1.0f / D_);
  float rstd = rsqrtf(s2 * (1.0f / D_) - mean * mean + 1e-5f);
  f32x4 gg = *(const f32x4*)(g + tx * 4);
  f32x4 bb = *(const f32x4*)(b + tx * 4);
  f32x4 oo;
#pragma unroll
  for (int j = 0; j < 4; j++) oo[j] = (v[j] - mean) * rstd * gg[j] + bb[j];
  *(f32x4*)(ei + o) = oo;
  float pl[8] = {};
  const float* rr = rw + (size_t)(tx * 4) * 8;
#pragma unroll
  for (int j = 0; j < 4; j++)
#pragma unroll
    for (int e = 0; e < 8; e++) pl[e] += oo[j] * rr[j * 8 + e];
#pragma unroll
  for (int of = 32; of; of >>= 1)
#pragma unroll
    for (int e = 0; e < 8; e++) pl[e] += __shfl_down(pl[e], of);
  __shared__ float plw[4][8];
  if ((tx & 63) == 0)
#pragma unroll
    for (int e = 0; e < 8; e++) plw[tx >> 6][e] = pl[e];
  __syncthreads();
  if (tx == 0) {
    float p8[8];
#pragma unroll
    for (int e = 0; e < 8; e++)
      p8[e] = plw[0][e] + plw[1][e] + plw[2][e] + plw[3][e];
    float mx = p8[0];
#pragma unroll
    for (int e = 1; e < 8; e++) mx = fmaxf(mx, p8[e]);
    float pr[8];
#pragma unroll
    for (int e = 0; e < 8; e++) pr[e] = __expf(p8[e] - mx);
    int i1 = 0;
#pragma unroll
    for (int e = 1; e < 8; e++)
      if (pr[e] > pr[i1]) i1 = e;
    int i2 = (i1 == 0) ? 1 : 0;
#pragma unroll
    for (int e = 0; e < 8; e++)
      if (e != i1 && pr[e] > pr[i2]) i2 = e;
    float v1 = pr[i1], v2 = pr[i2];
    float inv = 1.f / (v1 + v2);
    int t = row;
    idx2[t * 2] = i1;
    idx2[t * 2 + 1] = i2;
    wts2[t * 2] = v1 * inv;
    wts2[t * 2 + 1] = v2 * inv;
  }
}

// ---- per-block expert histogram via LDS atomics ----
__global__ __launch_bounds__(512) void hist_kernel(const int* __restrict__ idx2,
                                                   int* __restrict__ pos2,
                                                   int* __restrict__ blockcnt) {
  __shared__ int cnt[8];
  int tx = threadIdx.x;
  if (tx < 8) cnt[tx] = 0;
  __syncthreads();
  int entry = blockIdx.x * 512 + tx;
  int e = idx2[entry];
  pos2[entry] = atomicAdd(&cnt[e], 1);
  __syncthreads();
  if (tx < 8) blockcnt[blockIdx.x * 8 + tx] = cnt[tx];
}

// ---- scan: per-expert prefix over block counts; padded expert offsets ----
__global__ __launch_bounds__(128) void scan_kernel(const int* __restrict__ blockcnt,
                                                   int* __restrict__ offs,
                                                   int* __restrict__ counts,
                                                   int* __restrict__ gbase) {
  __shared__ int c[HB_][8];
  __shared__ int tot[8];
  __shared__ int eoff[9];
  int tx = threadIdx.x;
  c[tx >> 3][tx & 7] = blockcnt[tx];
  __syncthreads();
  if (tx < 8) {
    int s = 0;
    for (int b2 = 0; b2 < HB_; b2++) {
      int v = c[b2][tx];
      c[b2][tx] = s;
      s += v;
    }
    tot[tx] = s;
    counts[tx] = s;
  }
  __syncthreads();
  if (tx == 0) {
    int o = 0;
    for (int e = 0; e < 8; e++) {
      eoff[e] = o;
      o += ((tot[e] + 255) >> 8) << 8;
    }
    eoff[8] = o;
    for (int e = 0; e < 9; e++) offs[e] = eoff[e];
  }
  __syncthreads();
  gbase[tx] = eoff[tx & 7] + c[tx >> 3][tx & 7];
}

// ---- slots: pure loads ----
__global__ __launch_bounds__(256) void slot_kernel(const int* __restrict__ idx2,
                                                   const int* __restrict__ pos2,
                                                   const int* __restrict__ gbase,
                                                   int* __restrict__ elist,
                                                   int* __restrict__ slots) {
  int entry = blockIdx.x * 256 + threadIdx.x;
  int e = idx2[entry];
  int slot = gbase[(entry >> 9) * 8 + e] + pos2[entry];
  elist[slot] = entry >> 1;
  slots[entry] = slot;
}

// ------- transpose (+cvt): in (R,C) -> out (C,R) -----
template <int SPLIT>
__global__ __launch_bounds__(256) void transpose_cvt(const float* __restrict__ in,
                                                     short* __restrict__ out, int R,
                                                     int C) {
  __shared__ float t[32][33];
  size_t PS = (size_t)R * C;
  const float* inm = in + (size_t)blockIdx.z * PS;
  short* outm = out + (size_t)blockIdx.z * PS * (SPLIT ? 2 : 1);
  int r = threadIdx.x >> 3;
  int c4 = (threadIdx.x & 7) * 4;
  f32x4 v = *(const f32x4*)(inm + (size_t)(blockIdx.y * 32 + r) * C + blockIdx.x * 32 + c4);
#pragma unroll
  for (int i = 0; i < 4; i++) t[r][c4 + i] = v[i];
  __syncthreads();
  s16x4 oh, ol;
#pragma unroll
  for (int i = 0; i < 4; i++) {
    float val = t[c4 + i][r];
    if (SPLIT) {
      BfPair p = split2(val);
      oh[i] = p.hi;
      ol[i] = p.lo;
    } else {
      oh[i] = f2bf(val);
    }
  }
  size_t oidx = (size_t)(blockIdx.x * 32 + r) * R + blockIdx.y * 32 + c4;
  *(s16x4*)(outm + oidx) = oh;
  if (SPLIT) *(s16x4*)(outm + PS + oidx) = ol;
}

// ---- 4 dense DxD weights in one launch; split planes out ----
__global__ __launch_bounds__(256) void transpose_cvt4(
    const float* __restrict__ w0, const float* __restrict__ w1,
    const float* __restrict__ w2, const float* __restrict__ w3,
    short* __restrict__ out) {
  __shared__ float t[32][33];
  int z = blockIdx.z;
  const float* inm = (z == 0) ? w0 : (z == 1) ? w1 : (z == 2) ? w2 : w3;
  short* outm = out + (size_t)z * (2 * DD_);
  int r = threadIdx.x >> 3;
  int c4 = (threadIdx.x & 7) * 4;
  f32x4 v = *(const f32x4*)(inm + (size_t)(blockIdx.y * 32 + r) * D_ + blockIdx.x * 32 + c4);
#pragma unroll
  for (int i = 0; i < 4; i++) t[r][c4 + i] = v[i];
  __syncthreads();
  s16x4 oh, ol;
#pragma unroll
  for (int i = 0; i < 4; i++) {
    BfPair p = split2(t[c4 + i][r]);
    oh[i] = p.hi;
    ol[i] = p.lo;
  }
  size_t oidx = (size_t)(blockIdx.x * 32 + r) * D_ + blockIdx.y * 32 + c4;
  *(s16x4*)(outm + oidx) = oh;
  *(s16x4*)(outm + DD_ + oidx) = ol;
}

// ======== split GEMMs: 256x128 tile, 8 waves (4M x 2N), BK=32 ========

// ---- batched k/v/r split GEMM (r13 best body: 4-buffer, single-stage) ----
__global__ __launch_bounds__(512) void gemm_kvr(const short* __restrict__ X,
                                                const short* __restrict__ W,
                                                float* __restrict__ KVR) {
  __shared__ __align__(16) short Ah[256 * 32], Al[256 * 32];
  __shared__ __align__(16) short Bh[128 * 32], Bl[128 * 32];
  int tx = threadIdx.x;
  int lane = tx & 63;
  int orig = blockIdx.x + (blockIdx.y << 3) + (blockIdx.z << 7);
  int wgid = (orig & 7) * 48 + (orig >> 3);  // nwg=384, q=48
  int z = wgid >> 7;
  int rem = wgid & 127;
  int colStart = (rem & 7) * 128;
  int rowStart = (rem >> 3) * 256;
  const short* A0 = X + (size_t)z * (2 * MD_) + (size_t)rowStart * D_;
  const short* B0 = W + (size_t)z * (2 * DD_) + (size_t)colStart * D_;
  float* C = KVR + (size_t)z * MD_;
  int wave = tx >> 6, wm = wave >> 1, wn = wave & 1;
  f32x4 acc[4][4] = {};
  for (int k0 = 0; k0 < D_; k0 += 32) {
#pragma unroll
    for (int i = 0; i < 2; i++) {  // A planes: 2 chunks/thread each
      int c = i * 512 + tx;
      int row = c >> 2;
      int kb = swz(row, c & 3) * 16;
      size_t go = (size_t)row * (D_ * 2) + (size_t)k0 * 2 + kb;
      size_t lo = (size_t)(i * 512 + (tx & ~63)) * 16;
      gload_lds16((const char*)A0 + go, (char*)Ah + lo);
      gload_lds16((const char*)A0 + MD_ * 2 + go, (char*)Al + lo);
    }
    {  // B planes: 1 chunk/thread each
      int row = tx >> 2;
      int kb = swz(row, tx & 3) * 16;
      size_t go = (size_t)row * (D_ * 2) + (size_t)k0 * 2 + kb;
      size_t lo = (size_t)(tx & ~63) * 16;
      gload_lds16((const char*)B0 + go, (char*)Bh + lo);
      gload_lds16((const char*)B0 + DD_ * 2 + go, (char*)Bl + lo);
    }
    __syncthreads();
    short8 a[4], a2[4], b[4], b2[4];
#pragma unroll
    for (int m = 0; m < 4; m++) {
      int rr_ = wm * 64 + m * 16 + (lane & 15);
      int ro = rr_ * 32 + swz(rr_, lane >> 4) * 8;
      a[m] = *(const short8*)(Ah + ro);
      a2[m] = *(const short8*)(Al + ro);
    }
#pragma unroll
    for (int n = 0; n < 4; n++) {
      int rr_ = wn * 64 + n * 16 + (lane & 15);
      int ro = rr_ * 32 + swz(rr_, lane >> 4) * 8;
      b[n] = *(const short8*)(Bh + ro);
      b2[n] = *(const short8*)(Bl + ro);
    }
#pragma unroll
    for (int m = 0; m < 4; m++)
#pragma unroll
      for (int n = 0; n < 4; n++) {
        acc[m][n] = MFMA(a[m], b[n], acc[m][n]);
        acc[m][n] = MFMA(a2[m], b[n], acc[m][n]);
        acc[m][n] = MFMA(a[m], b2[n], acc[m][n]);
      }
    __syncthreads();
  }
  int r0 = rowStart + wm * 64 + ((lane >> 4) << 2);
  int cgl = colStart + wn * 64 + (lane & 15);
#pragma unroll
  for (int m = 0; m < 4; m++)
#pragma unroll
    for (int n = 0; n < 4; n++)
#pragma unroll
      for (int j = 0; j < 4; j++) {
        size_t idx = (size_t)(r0 + m * 16 + j) * D_ + cgl + n * 16;
        float vv = acc[m][n][j];
        if (z == 2) vv = 1.0f / (1.0f + __expf(-vv));
        C[idx] = vv;
      }
}

// ---- Wo split GEMM: K-split z in {0,1}; 4-buffer DOUBLE-BUFFERED counted
// pipeline (grid=256 = 1 block/CU, so 96KB LDS costs no co-residency) ----
__global__ __launch_bounds__(512) void gemm_wo(const short* __restrict__ A,
                                               const short* __restrict__ Bt,
                                               float* __restrict__ P) {
  __shared__ __align__(16) short Ah[2][256 * 32], Al[2][256 * 32];
  __shared__ __align__(16) short Bh[2][128 * 32], Bl[2][128 * 32];
  int tx = threadIdx.x;
  int lane = tx & 63;
  int orig = blockIdx.x + (blockIdx.y << 3) + (blockIdx.z << 7);
  int wgid = (orig & 7) * 32 + (orig >> 3);  // nwg=256, q=32
  int z = wgid >> 7;
  int rem = wgid & 127;
  int colStart = (rem & 7) * 128;
  int rowStart = (rem >> 3) * 256;
  const char* A0 = (const char*)(A + (size_t)rowStart * D_);
  const char* B0 = (const char*)(Bt + (size_t)colStart * D_);
  float* C = P + (size_t)z * MD_;
  int wave = tx >> 6, wm = wave >> 1, wn = wave & 1;
  int kbase = z * (D_ / 2);
  auto stage = [&](int buf, int k0) {  // exactly 6 gload_lds per thread
#pragma unroll
    for (int i = 0; i < 2; i++) {
      int c = i * 512 + tx;
      int row = c >> 2;
      int kb = swz(row, c & 3) * 16;
      size_t go = (size_t)row * (D_ * 2) + (size_t)k0 * 2 + kb;
      size_t lo = (size_t)(i * 512 + (tx & ~63)) * 16;
      gload_lds16(A0 + go, (char*)Ah[buf] + lo);
      gload_lds16(A0 + MD_ * 2 + go, (char*)Al[buf] + lo);
    }
    {
      int row = tx >> 2;
      int kb = swz(row, tx & 3) * 16;
      size_t go = (size_t)row * (D_ * 2) + (size_t)k0 * 2 + kb;
      size_t lo = (size_t)(tx & ~63) * 16;
      gload_lds16(B0 + go, (char*)Bh[buf] + lo);
      gload_lds16(B0 + DD_ * 2 + go, (char*)Bl[buf] + lo);
    }
  };
  f32x4 acc[4][4] = {};
  constexpr int NS = 16;  // (D_/2)/32
  int cur = 0;
  stage(0, kbase);
  for (int s = 0; s < NS; s++) {
    if (s + 1 < NS) {
      stage(cur ^ 1, kbase + (s + 1) * 32);
      asm volatile("s_waitcnt vmcnt(6)" ::: "memory");  // oldest 6 = cur buf
    } else {
      asm volatile("s_waitcnt vmcnt(0)" ::: "memory");
    }
    __builtin_amdgcn_s_barrier();
    short8 a[4], a2[4], b[4], b2[4];
#pragma unroll
    for (int m = 0; m < 4; m++) {
      int rr_ = wm * 64 + m * 16 + (lane & 15);
      int ro = rr_ * 32 + swz(rr_, lane >> 4) * 8;
      a[m] = *(const short8*)(Ah[cur] + ro);
      a2[m] = *(const short8*)(Al[cur] + ro);
    }
#pragma unroll
    for (int n = 0; n < 4; n++) {
      int rr_ = wn * 64 + n * 16 + (lane & 15);
      int ro = rr_ * 32 + swz(rr_, lane >> 4) * 8;
      b[n] = *(const short8*)(Bh[cur] + ro);
      b2[n] = *(const short8*)(Bl[cur] + ro);
    }
    __builtin_amdgcn_s_setprio(1);
#pragma unroll
    for (int m = 0; m < 4; m++)
#pragma unroll
      for (int n = 0; n < 4; n++) {
        acc[m][n] = MFMA(a[m], b[n], acc[m][n]);
        acc[m][n] = MFMA(a2[m], b[n], acc[m][n]);
        acc[m][n] = MFMA(a[m], b2[n], acc[m][n]);
      }
    __builtin_amdgcn_s_setprio(0);
    asm volatile("" ::: "memory");
    __builtin_amdgcn_s_barrier();
    cur ^= 1;
  }
  int r0 = rowStart + wm * 64 + ((lane >> 4) << 2);
  int cgl = colStart + wn * 64 + (lane & 15);
#pragma unroll
  for (int m = 0; m < 4; m++)
#pragma unroll
    for (int n = 0; n < 4; n++)
#pragma unroll
      for (int j = 0; j < 4; j++)
        C[(size_t)(r0 + m * 16 + j) * D_ + cgl + n * 16] = acc[m][n][j];
}

// ---- expert h GEMM: h = relu^2(Ak @ eWkT). 256x256 tile, 8 waves (2Mx4N),
// double-buffered counted-vmcnt pipeline: 64KB LDS -> 2 blocks/CU ----
__global__ __launch_bounds__(512) void gemm_exA(const short* __restrict__ A,
                                                const short* __restrict__ Bt,
                                                short* __restrict__ C,
                                                const int* __restrict__ offs) {
  __shared__ __align__(16) short As[2][256 * 32];
  __shared__ __align__(16) short Bs[2][256 * 32];
  int tx = threadIdx.x;
  int lane = tx & 63;
  int orig = blockIdx.x + (blockIdx.y << 3);  // grid (8,40)
  int wgid = (orig & 7) * 40 + (orig >> 3);   // nwg=320, q=40
  int colStart = (wgid & 7) * 256;
  int rowStart = (wgid >> 3) * 256;
  if (rowStart >= offs[8]) return;
  int e = 0;
  while (e < 7 && rowStart >= offs[e + 1]) e++;
  const char* Ag = (const char*)(A + (size_t)rowStart * D_);
  const char* Bg = (const char*)(Bt + (size_t)e * F_ * D_ + (size_t)colStart * D_);
  int wave = tx >> 6, wm = wave >> 2, wn = wave & 3;  // 2M x 4N
  auto stage = [&](int buf, int s) {  // exactly 4 gload_lds per thread
    size_t kb2 = (size_t)s << 6;
#pragma unroll
    for (int i = 0; i < 2; i++) {
      int c = i * 512 + tx;
      int row = c >> 2;
      int kb = swz(row, c & 3) * 16;
      size_t go = (size_t)row * (D_ * 2) + kb2 + kb;
      size_t lo = (size_t)(i * 512 + (tx & ~63)) * 16;
      gload_lds16(Ag + go, (char*)As[buf] + lo);
      gload_lds16(Bg + go, (char*)Bs[buf] + lo);
    }
  };
  f32x4 acc[8][4] = {};
  constexpr int NS = 32;
  int cur = 0;
  stage(0, 0);
  for (int s = 0; s < NS; s++) {
    if (s + 1 < NS) {
      stage(cur ^ 1, s + 1);
      asm volatile("s_waitcnt vmcnt(4)" ::: "memory");  // oldest 4 = cur buf
    } else {
      asm volatile("s_waitcnt vmcnt(0)" ::: "memory");
    }
    __builtin_amdgcn_s_barrier();
    short8 a[8], b[4];
#pragma unroll
    for (int m = 0; m < 8; m++) {
      int rr_ = wm * 128 + m * 16 + (lane & 15);
      a[m] = *(const short8*)(As[cur] + rr_ * 32 + swz(rr_, lane >> 4) * 8);
    }
#pragma unroll
    for (int n = 0; n < 4; n++) {
      int rr_ = wn * 64 + n * 16 + (lane & 15);
      b[n] = *(const short8*)(Bs[cur] + rr_ * 32 + swz(rr_, lane >> 4) * 8);
    }
    __builtin_amdgcn_s_setprio(1);
#pragma unroll
    for (int m = 0; m < 8; m++)
#pragma unroll
      for (int n = 0; n < 4; n++) acc[m][n] = MFMA(a[m], b[n], acc[m][n]);
    __builtin_amdgcn_s_setprio(0);
    asm volatile("" ::: "memory");
    __builtin_amdgcn_s_barrier();
    cur ^= 1;
  }
  int r0 = rowStart + wm * 128 + ((lane >> 4) << 2);
  int cgl = colStart + wn * 64 + (lane & 15);
#pragma unroll
  for (int m = 0; m < 8; m++)
#pragma unroll
    for (int n = 0; n < 4; n++)
#pragma unroll
      for (int j = 0; j < 4; j++) {
        size_t idx = (size_t)(r0 + m * 16 + j) * F_ + cgl + n * 16;
        float vv = acc[m][n][j];
        vv = vv > 0.f ? vv * vv : 0.f;
        C[idx] = f2bf(vv);
      }
}

// ---- merged expert GEMMs: 256x256 tile pipelined; z=0 kvb=h@eWvT (K=F),
// z=1 rrb=sig(Ar@eWrT) (K=D). 64KB LDS -> 2 blocks/CU ----
__global__ __launch_bounds__(512) void gemm_ex2(
    const short* __restrict__ h, const short* __restrict__ eWvT,
    short* __restrict__ kvb, const short* __restrict__ Ar,
    const short* __restrict__ eWrT, short* __restrict__ rrb,
    const int* __restrict__ offs) {
  __shared__ __align__(16) short As[2][256 * 32];
  __shared__ __align__(16) short Bs[2][256 * 32];
  int tx = threadIdx.x;
  int lane = tx & 63;
  int zz = blockIdx.z;
  int orig = blockIdx.x + (blockIdx.y << 2);  // grid (4,40,2)
  int wgid = (orig & 7) * 20 + (orig >> 3);   // per-slice nwg=160, q=20
  int colStart = (wgid & 3) * 256;
  int rowStart = (wgid >> 2) * 256;
  if (rowStart >= offs[8]) return;
  int e = 0;
  while (e < 7 && rowStart >= offs[e + 1]) e++;
  int K = zz ? D_ : F_;
  const char* Ag = (const char*)((zz ? Ar : h) + (size_t)rowStart * K);
  const char* Bg =
      (const char*)((zz ? eWrT : eWvT) + (size_t)e * D_ * K + (size_t)colStart * K);
  int wave = tx >> 6, wm = wave >> 2, wn = wave & 3;  // 2M x 4N
  const int NS = K / 32;
  auto stage = [&](int buf, int s) {  // exactly 4 gload_lds per thread
    size_t kb2 = (size_t)s << 6;
#pragma unroll
    for (int i = 0; i < 2; i++) {
      int c = i * 512 + tx;
      int row = c >> 2;
      int kb = swz(row, c & 3) * 16;
      size_t go = (size_t)row * ((size_t)K * 2) + kb2 + kb;
      size_t lo = (size_t)(i * 512 + (tx & ~63)) * 16;
      gload_lds16(Ag + go, (char*)As[buf] + lo);
      gload_lds16(Bg + go, (char*)Bs[buf] + lo);
    }
  };
  f32x4 acc[8][4] = {};
  int cur = 0;
  stage(0, 0);
  for (int s = 0; s < NS; s++) {
    if (s + 1 < NS) {
      stage(cur ^ 1, s + 1);
      asm volatile("s_waitcnt vmcnt(4)" ::: "memory");
    } else {
      asm volatile("s_waitcnt vmcnt(0)" ::: "memory");
    }
    __builtin_amdgcn_s_barrier();
    short8 a[8], b[4];
#pragma unroll
    for (int m = 0; m < 8; m++) {
      int rr_ = wm * 128 + m * 16 + (lane & 15);
      a[m] = *(const short8*)(As[cur] + rr_ * 32 + swz(rr_, lane >> 4) * 8);
    }
#pragma unroll
    for (int n = 0; n < 4; n++) {
      int rr_ = wn * 64 + n * 16 + (lane & 15);
      b[n] = *(const short8*)(Bs[cur] + rr_ * 32 + swz(rr_, lane >> 4) * 8);
    }
    __builtin_amdgcn_s_setprio(1);
#pragma unroll
    for (int m = 0; m < 8; m++)
#pragma unroll
      for (int n = 0; n < 4; n++) acc[m][n] = MFMA(a[m], b[n], acc[m][n]);
    __builtin_amdgcn_s_setprio(0);
    asm volatile("" ::: "memory");
    __builtin_amdgcn_s_barrier();
    cur ^= 1;
  }
  short* C = zz ? rrb : kvb;
  int r0 = rowStart + wm * 128 + ((lane >> 4) << 2);
  int cgl = colStart + wn * 64 + (lane & 15);
#pragma unroll
  for (int m = 0; m < 8; m++)
#pragma unroll
    for (int n = 0; n < 4; n++)
#pragma unroll
      for (int j = 0; j < 4; j++) {
        size_t idx = (size_t)(r0 + m * 16 + j) * D_ + cgl + n * 16;
        float vv = acc[m][n][j];
        if (zz) vv = 1.0f / (1.0f + __expf(-vv));
        C[idx] = f2bf(vv);
      }
}

// ---------------- WKV chunked scan ----------------
__global__ __launch_bounds__(256) void wkv_chunk_kernel(const float* __restrict__ k,
                                                        const float* __restrict__ v,
                                                        const float* __restrict__ td,
                                                        float* __restrict__ chA,
                                                        float* __restrict__ chB) {
  int d = blockIdx.x * 256 + threadIdx.x;
  int c = blockIdx.y;
  int b = blockIdx.z;
  float w = -__expf(td[d]);
  float dec = __expf(w);
  float A = 0.f, Bb = 0.f;
  size_t base = ((size_t)b * S_ + (size_t)c * L_) * D_ + d;
  for (int i = 0; i < L_; i++) {
    float kt = k[base + (size_t)i * D_];
    float vt = v[base + (size_t)i * D_];
    float ek = __expf(kt);
    A = fmaf(A, dec, ek * vt);
    Bb = fmaf(Bb, dec, ek);
  }
  size_t o = ((size_t)b * NC_ + c) * D_ + d;
  chA[o] = A;
  chB[o] = Bb;
}

__global__ __launch_bounds__(256) void wkv_carry_kernel(const float* __restrict__ chA,
                                                        const float* __restrict__ chB,
                                                        const float* __restrict__ td,
                                                        float* __restrict__ caA,
                                                        float* __restrict__ caB) {
  int d = blockIdx.x * 256 + threadIdx.x;
  int b = blockIdx.y;
  float w = -__expf(td[d]);
  float decL = __expf(w * (float)L_);
  float A = 0.f, Bb = 0.f;
  for (int c = 0; c < NC_; c++) {
    size_t o = ((size_t)b * NC_ + c) * D_ + d;
    caA[o] = A;
    caB[o] = Bb;
    A = fmaf(A, decL, chA[o]);
    Bb = fmaf(Bb, decL, chB[o]);
  }
}

__global__ __launch_bounds__(256) void wkv_out_kernel(
    const float* __restrict__ k, const float* __restrict__ v,
    const float* __restrict__ r, const float* __restrict__ caA,
    const float* __restrict__ caB, const float* __restrict__ td,
    const float* __restrict__ tf, short* __restrict__ rwkv) {
  int d = blockIdx.x * 256 + threadIdx.x;
  int c = blockIdx.y;
  int b = blockIdx.z;
  float w = -__expf(td[d]);
  float dec = __expf(w);
  float eu = __expf(tf[d]);
  size_t co = ((size_t)b * NC_ + c) * D_ + d;
  float A = caA[co], Bb = caB[co];
  size_t base = ((size_t)b * S_ + (size_t)c * L_) * D_ + d;
  for (int i = 0; i < L_; i++) {
    size_t ix = base + (size_t)i * D_;
    float kt = k[ix], vt = v[ix], rt = r[ix];
    float ek = __expf(kt);
    float euk = eu * ek;
    float wkv = (A + euk * vt) / (Bb + euk);
    BfPair p = split2(rt * wkv);
    rwkv[ix] = p.hi;
    rwkv[MD_ + ix] = p.lo;
    A = fmaf(A, dec, ek * vt);
    Bb = fmaf(Bb, dec, ek);
  }
}

// ---------------- MoE gather + channel-mix (build Ak/Ar, bf16) ----------------
__global__ __launch_bounds__(256) void gather_mix_kernel(
    const float* __restrict__ ei, const float* __restrict__ cmk,
    const float* __restrict__ cmr, const int* __restrict__ offs,
    const int* __restrict__ counts, const int* __restrict__ elist,
    short* __restrict__ Ak, short* __restrict__ Ar) {
  int row = blockIdx.x;
  if (row >= offs[8]) return;
  int e = 0;
  while (e < 7 && row >= offs[e + 1]) e++;
  int p = row - offs[e];
  int d = threadIdx.x * 4;
  size_t ro = (size_t)row * D_ + d;
  if (p >= counts[e]) {
    s16x4 z = {0, 0, 0, 0};
    *(s16x4*)(Ak + ro) = z;
    *(s16x4*)(Ar + ro) = z;
    return;
  }
  int t = elist[row];
  int s = t & (S_ - 1);
  f32x4 cur = *(const f32x4*)(ei + (size_t)t * D_ + d);
  f32x4 prev = {0.f, 0.f, 0.f, 0.f};
  if (s > 0) prev = *(const f32x4*)(ei + (size_t)(t - 1) * D_ + d);
  f32x4 mk = *(const f32x4*)(cmk + (size_t)e * D_ + d);
  f32x4 mr = *(const f32x4*)(cmr + (size_t)e * D_ + d);
  s16x4 ok, orr;
#pragma unroll
  for (int j = 0; j < 4; j++) {
    ok[j] = f2bf(cur[j] * mk[j] + prev[j] * (1.f - mk[j]));
    orr[j] = f2bf(cur[j] * mr[j] + prev[j] * (1.f - mr[j]));
  }
  *(s16x4*)(Ak + ro) = ok;
  *(s16x4*)(Ar + ro) = orr;
}

// ---------------- final: out = xout + sum_j w_j * rr * kv ----------------
__global__ __launch_bounds__(256) void final_kernel(
    const float* __restrict__ xout, const short* __restrict__ rrb,
    const short* __restrict__ kvb, const int* __restrict__ slots,
    const float* __restrict__ wts2, float* __restrict__ out) {
  size_t i4 = (size_t)blockIdx.x * 256 + threadIdx.x;
  size_t el = i4 * 4;
  int t = (int)(el >> 10);
  int d = (int)(el & (D_ - 1));
  int s0 = slots[t * 2], s1 = slots[t * 2 + 1];
  float w0 = wts2[t * 2], w1 = wts2[t * 2 + 1];
  f32x4 xo = *(const f32x4*)(xout + el);
  s16x4 r0 = *(const s16x4*)(rrb + (size_t)s0 * D_ + d);
  s16x4 k0 = *(const s16x4*)(kvb + (size_t)s0 * D_ + d);
  s16x4 r1 = *(const s16x4*)(rrb + (size_t)s1 * D_ + d);
  s16x4 k1 = *(const s16x4*)(kvb + (size_t)s1 * D_ + d);
  f32x4 o;
#pragma unroll
  for (int j = 0; j < 4; j++)
    o[j] = xo[j] + w0 * bf2f(r0[j]) * bf2f(k0[j]) + w1 * bf2f(r1[j]) * bf2f(k1[j]);
  *(f32x4*)(out + el) = o;
}

// ============================================================================
extern "C" void kernel_launch(void* const* d_in, const int* in_sizes, int n_in,
                              void* d_out, int out_size, void* d_ws, size_t ws_size,
                              hipStream_t stream) {
  (void)in_sizes; (void)n_in; (void)out_size; (void)ws_size;
  const float* x = (const float*)d_in[0];
  const float* ln1g = (const float*)d_in[1];
  const float* ln1b = (const float*)d_in[2];
  const float* ln2g = (const float*)d_in[3];
  const float* ln2b = (const float*)d_in[4];
  const float* muk = (const float*)d_in[5];
  const float* muv = (const float*)d_in[6];
  const float* mur = (const float*)d_in[7];
  const float* tdec = (const float*)d_in[8];
  const float* tfirst = (const float*)d_in[9];
  const float* Wk = (const float*)d_in[10];
  const float* Wv = (const float*)d_in[11];
  const float* Wr = (const float*)d_in[12];
  const float* Wo = (const float*)d_in[13];
  const float* rw = (const float*)d_in[14];
  const float* cmk = (const float*)d_in[15];
  const float* cmr = (const float*)d_in[16];
  const float* eWk = (const float*)d_in[17];
  const float* eWv = (const float*)d_in[18];
  const float* eWr = (const float*)d_in[19];
  float* out = (float*)d_out;

  char* w = (char*)d_ws;
  size_t off = 0;
  auto alloc = [&](size_t bytes) {
    size_t o = off;
    off = (off + bytes + 255) & ~(size_t)255;
    return o;
  };
  const size_t szDD2x2 = DD_ * 2 * 2;
  size_t o_WT = alloc(4 * szDD2x2);
  size_t o_WkT = o_WT, o_WoT = o_WT + 3 * szDD2x2;
  size_t o_eWkT = alloc((size_t)E_ * D_ * F_ * 2);
  size_t o_eWvT = alloc((size_t)E_ * F_ * D_ * 2);
  size_t o_eWrT = alloc((size_t)E_ * D_ * D_ * 2);
  size_t o_xout = alloc(MD_ * 4);
  size_t o_ei = alloc(MD_ * 4);
  size_t o_counts = alloc(64);
  size_t o_offs = alloc(64);
  size_t o_idx2 = alloc((size_t)M_ * 2 * 4);
  size_t o_wts2 = alloc((size_t)M_ * 2 * 4);
  size_t o_pos2 = alloc((size_t)M_ * 2 * 4);
  size_t o_blockcnt = alloc((size_t)HB_ * 8 * 4);
  size_t o_gbase = alloc((size_t)HB_ * 8 * 4);
  size_t o_elist = alloc((size_t)PC_ * 4);
  size_t o_slots = alloc((size_t)M_ * 2 * 4);
  size_t poolBase = off;
  size_t off1 = poolBase;
  auto alloc1 = [&](size_t bytes) {
    size_t o = off1;
    off1 = (off1 + bytes + 255) & ~(size_t)255;
    return o;
  };
  size_t o_rwkv = alloc1(MD_ * 2 * 2);
  size_t o_xk = alloc1(MD_ * 2 * 2);
  size_t o_xv = alloc1(MD_ * 2 * 2);
  size_t o_xr = alloc1(MD_ * 2 * 2);
  size_t o_k = alloc1(MD_ * 4);
  size_t o_v = alloc1(MD_ * 4);
  size_t o_r = alloc1(MD_ * 4);
  size_t o_chA = alloc1((size_t)B_ * NC_ * D_ * 4);
  size_t o_chB = alloc1((size_t)B_ * NC_ * D_ * 4);
  size_t o_caA = alloc1((size_t)B_ * NC_ * D_ * 4);
  size_t o_caB = alloc1((size_t)B_ * NC_ * D_ * 4);
  size_t o_P = o_k;  // alias: k/v dead after wkv_out
  size_t off2 = poolBase;
  auto alloc2 = [&](size_t bytes) {
    size_t o = off2;
    off2 = (off2 + bytes + 255) & ~(size_t)255;
    return o;
  };
  size_t o_Ak = alloc2((size_t)PC_ * D_ * 2);
  size_t o_Ar = alloc2((size_t)PC_ * D_ * 2);
  size_t o_h = alloc2((size_t)PC_ * F_ * 2);
  size_t o_kvb = alloc2((size_t)PC_ * D_ * 2);
  size_t o_rrb = alloc2((size_t)PC_ * D_ * 2);

#define WP(T, o) ((T*)(w + (o)))

  transpose_cvt4<<<dim3(32, 32, 4), 256, 0, stream>>>(Wk, Wv, Wr, Wo,
                                                      WP(short, o_WkT));
  transpose_cvt<0><<<dim3(F_ / 32, D_ / 32, E_), 256, 0, stream>>>(eWk, WP(short, o_eWkT), D_, F_);
  transpose_cvt<0><<<dim3(D_ / 32, F_ / 32, E_), 256, 0, stream>>>(eWv, WP(short, o_eWvT), F_, D_);
  transpose_cvt<0><<<dim3(D_ / 32, D_ / 32, E_), 256, 0, stream>>>(eWr, WP(short, o_eWrT), D_, D_);

  lnmix_kernel<<<M_, 256, 0, stream>>>(x, ln1g, ln1b, muk, muv, mur,
                                       WP(short, o_xk), WP(short, o_xv),
                                       WP(short, o_xr));

  gemm_kvr<<<dim3(8, 16, 3), 512, 0, stream>>>(WP(short, o_xk), WP(short, o_WkT),
                                               WP(float, o_k));

  wkv_chunk_kernel<<<dim3(D_ / 256, NC_, B_), 256, 0, stream>>>(
      WP(float, o_k), WP(float, o_v), tdec, WP(float, o_chA), WP(float, o_chB));
  wkv_carry_kernel<<<dim3(D_ / 256, B_), 256, 0, stream>>>(
      WP(float, o_chA), WP(float, o_chB), tdec, WP(float, o_caA), WP(float, o_caB));
  wkv_out_kernel<<<dim3(D_ / 256, NC_, B_), 256, 0, stream>>>(
      WP(float, o_k), WP(float, o_v), WP(float, o_r), WP(float, o_caA),
      WP(float, o_caB), tdec, tfirst, WP(short, o_rwkv));

  gemm_wo<<<dim3(8, 16, 2), 512, 0, stream>>>(WP(short, o_rwkv), WP(short, o_WoT),
                                              WP(float, o_P));
  ln2_router<<<M_, 256, 0, stream>>>(x, WP(float, o_P), ln2g, ln2b, rw,
                                     WP(float, o_xout), WP(float, o_ei),
                                     WP(int, o_idx2), WP(float, o_wts2));

  hist_kernel<<<HB_, 512, 0, stream>>>(WP(int, o_idx2), WP(int, o_pos2),
                                       WP(int, o_blockcnt));
  scan_kernel<<<1, 128, 0, stream>>>(WP(int, o_blockcnt), WP(int, o_offs),
                                     WP(int, o_counts), WP(int, o_gbase));
  slot_kernel<<<(2 * M_) / 256, 256, 0, stream>>>(WP(int, o_idx2), WP(int, o_pos2),
                                                  WP(int, o_gbase), WP(int, o_elist),
                                                  WP(int, o_slots));
  gather_mix_kernel<<<PC_, 256, 0, stream>>>(WP(float, o_ei), cmk, cmr, WP(int, o_offs),
                                             WP(int, o_counts), WP(int, o_elist),
                                             WP(short, o_Ak), WP(short, o_Ar));

  // expert GEMMs: 256x256 tiles, 2 blocks/CU, pipelined
  gemm_exA<<<dim3(8, 40), 512, 0, stream>>>(WP(short, o_Ak), WP(short, o_eWkT),
                                            WP(short, o_h), WP(int, o_offs));
  gemm_ex2<<<dim3(4, 40, 2), 512, 0, stream>>>(
      WP(short, o_h), WP(short, o_eWvT), WP(short, o_kvb), WP(short, o_Ar),
      WP(short, o_eWrT), WP(short, o_rrb), WP(int, o_offs));

  final_kernel<<<M_ * D_ / 4 / 256, 256, 0, stream>>>(
      WP(float, o_xout), WP(short, o_rrb), WP(short, o_kvb), WP(int, o_slots),
      WP(float, o_wts2), out);
#undef WP
}

// Round 17
// 433.116 us; speedup vs baseline: 1.0726x; 1.0726x over previous
//
#include <hip/hip_runtime.h>
#include <hip/hip_bf16.h>
#include <stdint.h>

#define DEVI __device__ __forceinline__

typedef __attribute__((ext_vector_type(4))) float f32x4;
typedef __attribute__((ext_vector_type(8))) short short8;
typedef __attribute__((ext_vector_type(4))) short s16x4;

constexpr int B_ = 2, S_ = 2048, D_ = 1024, E_ = 8, F_ = 2048;
constexpr int M_ = B_ * S_;        // 4096 tokens
constexpr int PC_ = 10240;         // padded pair capacity (8192 + 8*256)
constexpr int NC_ = 64, L_ = 32;   // scan chunking: NC_*L_ == S_
constexpr int HB_ = 16;            // hist blocks (HB_*512 == 2*M_)
constexpr size_t MD_ = (size_t)M_ * D_;
constexpr size_t DD_ = (size_t)D_ * D_;

DEVI short f2bf(float f) {
  uint32_t u = __float_as_uint(f);
  u = (u + 0x7fffu + ((u >> 16) & 1u)) >> 16;
  return (short)u;
}
DEVI float bf2f(short s) { return __uint_as_float(((uint32_t)(uint16_t)s) << 16); }
struct BfPair { short hi, lo; };
DEVI BfPair split2(float f) {
  BfPair p;
  p.hi = f2bf(f);
  p.lo = f2bf(f - bf2f(p.hi));
  return p;
}

DEVI void gload_lds16(const void* g, void* l) {
  __builtin_amdgcn_global_load_lds(
      (const __attribute__((address_space(1))) unsigned int*)g,
      (__attribute__((address_space(3))) unsigned int*)l, 16, 0, 0);
}

// bank-conflict swizzle: 16B-slot XOR within a 64B row (involution; applied
// to the global SOURCE slot at stage time and to the READ slot — LDS dest
// stays linear as required by global_load_lds).
DEVI int swz(int row, int slot) { return slot ^ ((row >> 1) & 3); }

#define MFMA(a, b, c) __builtin_amdgcn_mfma_f32_16x16x32_bf16((a), (b), (c), 0, 0, 0)

// ---- fused LN1 + time-mix ----
__global__ __launch_bounds__(256) void lnmix_kernel(
    const float* __restrict__ x, const float* __restrict__ g,
    const float* __restrict__ b, const float* __restrict__ muk,
    const float* __restrict__ muv, const float* __restrict__ mur,
    short* __restrict__ xk, short* __restrict__ xv, short* __restrict__ xr) {
  int row = blockIdx.x;
  int tx = threadIdx.x;
  int s = row & (S_ - 1);
  size_t o = (size_t)row * D_ + tx * 4;
  f32x4 cur = *(const f32x4*)(x + o);
  f32x4 prv = {0.f, 0.f, 0.f, 0.f};
  if (s > 0) prv = *(const f32x4*)(x + o - D_);
  float a0 = cur[0] + cur[1] + cur[2] + cur[3];
  float a1 = cur[0] * cur[0] + cur[1] * cur[1] + cur[2] * cur[2] + cur[3] * cur[3];
  float a2 = prv[0] + prv[1] + prv[2] + prv[3];
  float a3 = prv[0] * prv[0] + prv[1] * prv[1] + prv[2] * prv[2] + prv[3] * prv[3];
#pragma unroll
  for (int o2 = 32; o2; o2 >>= 1) {
    a0 += __shfl_down(a0, o2);
    a1 += __shfl_down(a1, o2);
    a2 += __shfl_down(a2, o2);
    a3 += __shfl_down(a3, o2);
  }
  __shared__ float rd[4][4];
  if ((tx & 63) == 0) {
    rd[tx >> 6][0] = a0; rd[tx >> 6][1] = a1;
    rd[tx >> 6][2] = a2; rd[tx >> 6][3] = a3;
  }
  __syncthreads();
  a0 = rd[0][0] + rd[1][0] + rd[2][0] + rd[3][0];
  a1 = rd[0][1] + rd[1][1] + rd[2][1] + rd[3][1];
  a2 = rd[0][2] + rd[1][2] + rd[2][2] + rd[3][2];
  a3 = rd[0][3] + rd[1][3] + rd[2][3] + rd[3][3];
  float mc = a0 * (1.0f / D_);
  float rc = rsqrtf(a1 * (1.0f / D_) - mc * mc + 1e-5f);
  float mp = a2 * (1.0f / D_);
  float rp = rsqrtf(a3 * (1.0f / D_) - mp * mp + 1e-5f);
  int d = tx * 4;
  f32x4 gg = *(const f32x4*)(g + d);
  f32x4 bb = *(const f32x4*)(b + d);
  f32x4 mk = *(const f32x4*)(muk + d);
  f32x4 mv = *(const f32x4*)(muv + d);
  f32x4 mr = *(const f32x4*)(mur + d);
  s16x4 okh, okl, ovh, ovl, orh, orl;
#pragma unroll
  for (int j = 0; j < 4; j++) {
    float c = (cur[j] - mc) * rc * gg[j] + bb[j];
    float p = (s > 0) ? (prv[j] - mp) * rp * gg[j] + bb[j] : 0.f;
    BfPair pk = split2(c * mk[j] + p * (1.f - mk[j]));
    BfPair pv = split2(c * mv[j] + p * (1.f - mv[j]));
    BfPair pr = split2(c * mr[j] + p * (1.f - mr[j]));
    okh[j] = pk.hi; okl[j] = pk.lo;
    ovh[j] = pv.hi; ovl[j] = pv.lo;
    orh[j] = pr.hi; orl[j] = pr.lo;
  }
  *(s16x4*)(xk + o) = okh;
  *(s16x4*)(xk + MD_ + o) = okl;
  *(s16x4*)(xv + o) = ovh;
  *(s16x4*)(xv + MD_ + o) = ovl;
  *(s16x4*)(xr + o) = orh;
  *(s16x4*)(xr + MD_ + o) = orl;
}

// ---- fused: xout = x + P0+P1; ei = LN(xout); router logits+top2 (NO atomics)
__global__ __launch_bounds__(256) void ln2_router(
    const float* __restrict__ x, const float* __restrict__ P,
    const float* __restrict__ g, const float* __restrict__ b,
    const float* __restrict__ rw, float* __restrict__ xout,
    float* __restrict__ ei, int* __restrict__ idx2, float* __restrict__ wts2) {
  int row = blockIdx.x;
  int tx = threadIdx.x;
  size_t o = (size_t)row * D_ + tx * 4;
  f32x4 v = *(const f32x4*)(x + o);
  f32x4 p0 = *(const f32x4*)(P + o);
  f32x4 p1 = *(const f32x4*)(P + MD_ + o);
#pragma unroll
  for (int j = 0; j < 4; j++) v[j] += p0[j] + p1[j];
  *(f32x4*)(xout + o) = v;
  float s = v[0] + v[1] + v[2] + v[3];
  float s2 = v[0] * v[0] + v[1] * v[1] + v[2] * v[2] + v[3] * v[3];
#pragma unroll
  for (int of = 32; of; of >>= 1) {
    s += __shfl_down(s, of);
    s2 += __shfl_down(s2, of);
  }
  __shared__ float w1[4], w2[4];
  if ((tx & 63) == 0) { w1[tx >> 6] = s; w2[tx >> 6] = s2; }
  __syncthreads();
  s = w1[0] + w1[1] + w1[2] + w1[3];
  s2 = w2[0] + w2[1] + w2[2] + w2[3];
  float mean = s * (1.0f / D_);
  float rstd = rsqrtf(s2 * (1.0f / D_) - mean * mean + 1e-5f);
  f32x4 gg = *(const f32x4*)(g + tx * 4);
  f32x4 bb = *(const f32x4*)(b + tx * 4);
  f32x4 oo;
#pragma unroll
  for (int j = 0; j < 4; j++) oo[j] = (v[j] - mean) * rstd * gg[j] + bb[j];
  *(f32x4*)(ei + o) = oo;
  float pl[8] = {};
  const float* rr = rw + (size_t)(tx * 4) * 8;
#pragma unroll
  for (int j = 0; j < 4; j++)
#pragma unroll
    for (int e = 0; e < 8; e++) pl[e] += oo[j] * rr[j * 8 + e];
#pragma unroll
  for (int of = 32; of; of >>= 1)
#pragma unroll
    for (int e = 0; e < 8; e++) pl[e] += __shfl_down(pl[e], of);
  __shared__ float plw[4][8];
  if ((tx & 63) == 0)
#pragma unroll
    for (int e = 0; e < 8; e++) plw[tx >> 6][e] = pl[e];
  __syncthreads();
  if (tx == 0) {
    float p8[8];
#pragma unroll
    for (int e = 0; e < 8; e++)
      p8[e] = plw[0][e] + plw[1][e] + plw[2][e] + plw[3][e];
    float mx = p8[0];
#pragma unroll
    for (int e = 1; e < 8; e++) mx = fmaxf(mx, p8[e]);
    float pr[8];
#pragma unroll
    for (int e = 0; e < 8; e++) pr[e] = __expf(p8[e] - mx);
    int i1 = 0;
#pragma unroll
    for (int e = 1; e < 8; e++)
      if (pr[e] > pr[i1]) i1 = e;
    int i2 = (i1 == 0) ? 1 : 0;
#pragma unroll
    for (int e = 0; e < 8; e++)
      if (e != i1 && pr[e] > pr[i2]) i2 = e;
    float v1 = pr[i1], v2 = pr[i2];
    float inv = 1.f / (v1 + v2);
    int t = row;
    idx2[t * 2] = i1;
    idx2[t * 2 + 1] = i2;
    wts2[t * 2] = v1 * inv;
    wts2[t * 2 + 1] = v2 * inv;
  }
}

// ---- per-block expert histogram via LDS atomics ----
__global__ __launch_bounds__(512) void hist_kernel(const int* __restrict__ idx2,
                                                   int* __restrict__ pos2,
                                                   int* __restrict__ blockcnt) {
  __shared__ int cnt[8];
  int tx = threadIdx.x;
  if (tx < 8) cnt[tx] = 0;
  __syncthreads();
  int entry = blockIdx.x * 512 + tx;
  int e = idx2[entry];
  pos2[entry] = atomicAdd(&cnt[e], 1);
  __syncthreads();
  if (tx < 8) blockcnt[blockIdx.x * 8 + tx] = cnt[tx];
}

// ---- scan: per-expert prefix over block counts; padded expert offsets ----
__global__ __launch_bounds__(128) void scan_kernel(const int* __restrict__ blockcnt,
                                                   int* __restrict__ offs,
                                                   int* __restrict__ counts,
                                                   int* __restrict__ gbase) {
  __shared__ int c[HB_][8];
  __shared__ int tot[8];
  __shared__ int eoff[9];
  int tx = threadIdx.x;
  c[tx >> 3][tx & 7] = blockcnt[tx];
  __syncthreads();
  if (tx < 8) {
    int s = 0;
    for (int b2 = 0; b2 < HB_; b2++) {
      int v = c[b2][tx];
      c[b2][tx] = s;
      s += v;
    }
    tot[tx] = s;
    counts[tx] = s;
  }
  __syncthreads();
  if (tx == 0) {
    int o = 0;
    for (int e = 0; e < 8; e++) {
      eoff[e] = o;
      o += ((tot[e] + 255) >> 8) << 8;
    }
    eoff[8] = o;
    for (int e = 0; e < 9; e++) offs[e] = eoff[e];
  }
  __syncthreads();
  gbase[tx] = eoff[tx & 7] + c[tx >> 3][tx & 7];
}

// ---- slots: pure loads ----
__global__ __launch_bounds__(256) void slot_kernel(const int* __restrict__ idx2,
                                                   const int* __restrict__ pos2,
                                                   const int* __restrict__ gbase,
                                                   int* __restrict__ elist,
                                                   int* __restrict__ slots) {
  int entry = blockIdx.x * 256 + threadIdx.x;
  int e = idx2[entry];
  int slot = gbase[(entry >> 9) * 8 + e] + pos2[entry];
  elist[slot] = entry >> 1;
  slots[entry] = slot;
}

// ------- transpose (+cvt): in (R,C) -> out (C,R) -----
template <int SPLIT>
__global__ __launch_bounds__(256) void transpose_cvt(const float* __restrict__ in,
                                                     short* __restrict__ out, int R,
                                                     int C) {
  __shared__ float t[32][33];
  size_t PS = (size_t)R * C;
  const float* inm = in + (size_t)blockIdx.z * PS;
  short* outm = out + (size_t)blockIdx.z * PS * (SPLIT ? 2 : 1);
  int r = threadIdx.x >> 3;
  int c4 = (threadIdx.x & 7) * 4;
  f32x4 v = *(const f32x4*)(inm + (size_t)(blockIdx.y * 32 + r) * C + blockIdx.x * 32 + c4);
#pragma unroll
  for (int i = 0; i < 4; i++) t[r][c4 + i] = v[i];
  __syncthreads();
  s16x4 oh, ol;
#pragma unroll
  for (int i = 0; i < 4; i++) {
    float val = t[c4 + i][r];
    if (SPLIT) {
      BfPair p = split2(val);
      oh[i] = p.hi;
      ol[i] = p.lo;
    } else {
      oh[i] = f2bf(val);
    }
  }
  size_t oidx = (size_t)(blockIdx.x * 32 + r) * R + blockIdx.y * 32 + c4;
  *(s16x4*)(outm + oidx) = oh;
  if (SPLIT) *(s16x4*)(outm + PS + oidx) = ol;
}

// ---- 4 dense DxD weights in one launch; split planes out ----
__global__ __launch_bounds__(256) void transpose_cvt4(
    const float* __restrict__ w0, const float* __restrict__ w1,
    const float* __restrict__ w2, const float* __restrict__ w3,
    short* __restrict__ out) {
  __shared__ float t[32][33];
  int z = blockIdx.z;
  const float* inm = (z == 0) ? w0 : (z == 1) ? w1 : (z == 2) ? w2 : w3;
  short* outm = out + (size_t)z * (2 * DD_);
  int r = threadIdx.x >> 3;
  int c4 = (threadIdx.x & 7) * 4;
  f32x4 v = *(const f32x4*)(inm + (size_t)(blockIdx.y * 32 + r) * D_ + blockIdx.x * 32 + c4);
#pragma unroll
  for (int i = 0; i < 4; i++) t[r][c4 + i] = v[i];
  __syncthreads();
  s16x4 oh, ol;
#pragma unroll
  for (int i = 0; i < 4; i++) {
    BfPair p = split2(t[c4 + i][r]);
    oh[i] = p.hi;
    ol[i] = p.lo;
  }
  size_t oidx = (size_t)(blockIdx.x * 32 + r) * D_ + blockIdx.y * 32 + c4;
  *(s16x4*)(outm + oidx) = oh;
  *(s16x4*)(outm + DD_ + oidx) = ol;
}

// ======== 256x128 tile, 8 waves (4M x 2N), BK=32, swizzled LDS slots ========

// ---- batched k/v/r split GEMM (best body: 4-buffer, single-stage) ----
__global__ __launch_bounds__(512) void gemm_kvr(const short* __restrict__ X,
                                                const short* __restrict__ W,
                                                float* __restrict__ KVR) {
  __shared__ __align__(16) short Ah[256 * 32], Al[256 * 32];
  __shared__ __align__(16) short Bh[128 * 32], Bl[128 * 32];
  int tx = threadIdx.x;
  int lane = tx & 63;
  int orig = blockIdx.x + (blockIdx.y << 3) + (blockIdx.z << 7);
  int wgid = (orig & 7) * 48 + (orig >> 3);  // nwg=384, q=48
  int z = wgid >> 7;
  int rem = wgid & 127;
  int colStart = (rem & 7) * 128;
  int rowStart = (rem >> 3) * 256;
  const short* A0 = X + (size_t)z * (2 * MD_) + (size_t)rowStart * D_;
  const short* B0 = W + (size_t)z * (2 * DD_) + (size_t)colStart * D_;
  float* C = KVR + (size_t)z * MD_;
  int wave = tx >> 6, wm = wave >> 1, wn = wave & 1;
  f32x4 acc[4][4] = {};
  for (int k0 = 0; k0 < D_; k0 += 32) {
#pragma unroll
    for (int i = 0; i < 2; i++) {  // A planes: 2 chunks/thread each
      int c = i * 512 + tx;
      int row = c >> 2;
      int kb = swz(row, c & 3) * 16;
      size_t go = (size_t)row * (D_ * 2) + (size_t)k0 * 2 + kb;
      size_t lo = (size_t)(i * 512 + (tx & ~63)) * 16;
      gload_lds16((const char*)A0 + go, (char*)Ah + lo);
      gload_lds16((const char*)A0 + MD_ * 2 + go, (char*)Al + lo);
    }
    {  // B planes: 1 chunk/thread each
      int row = tx >> 2;
      int kb = swz(row, tx & 3) * 16;
      size_t go = (size_t)row * (D_ * 2) + (size_t)k0 * 2 + kb;
      size_t lo = (size_t)(tx & ~63) * 16;
      gload_lds16((const char*)B0 + go, (char*)Bh + lo);
      gload_lds16((const char*)B0 + DD_ * 2 + go, (char*)Bl + lo);
    }
    __syncthreads();
    short8 a[4], a2[4], b[4], b2[4];
#pragma unroll
    for (int m = 0; m < 4; m++) {
      int rr_ = wm * 64 + m * 16 + (lane & 15);
      int ro = rr_ * 32 + swz(rr_, lane >> 4) * 8;
      a[m] = *(const short8*)(Ah + ro);
      a2[m] = *(const short8*)(Al + ro);
    }
#pragma unroll
    for (int n = 0; n < 4; n++) {
      int rr_ = wn * 64 + n * 16 + (lane & 15);
      int ro = rr_ * 32 + swz(rr_, lane >> 4) * 8;
      b[n] = *(const short8*)(Bh + ro);
      b2[n] = *(const short8*)(Bl + ro);
    }
#pragma unroll
    for (int m = 0; m < 4; m++)
#pragma unroll
      for (int n = 0; n < 4; n++) {
        acc[m][n] = MFMA(a[m], b[n], acc[m][n]);
        acc[m][n] = MFMA(a2[m], b[n], acc[m][n]);
        acc[m][n] = MFMA(a[m], b2[n], acc[m][n]);
      }
    __syncthreads();
  }
  int r0 = rowStart + wm * 64 + ((lane >> 4) << 2);
  int cgl = colStart + wn * 64 + (lane & 15);
#pragma unroll
  for (int m = 0; m < 4; m++)
#pragma unroll
    for (int n = 0; n < 4; n++)
#pragma unroll
      for (int j = 0; j < 4; j++) {
        size_t idx = (size_t)(r0 + m * 16 + j) * D_ + cgl + n * 16;
        float vv = acc[m][n][j];
        if (z == 2) vv = 1.0f / (1.0f + __expf(-vv));
        C[idx] = vv;
      }
}

// ---- Wo split GEMM: K-split z in {0,1}; 4-buffer DOUBLE-BUFFERED counted
// pipeline (grid=256 = 1 block/CU, so 96KB LDS costs no co-residency) ----
__global__ __launch_bounds__(512) void gemm_wo(const short* __restrict__ A,
                                               const short* __restrict__ Bt,
                                               float* __restrict__ P) {
  __shared__ __align__(16) short Ah[2][256 * 32], Al[2][256 * 32];
  __shared__ __align__(16) short Bh[2][128 * 32], Bl[2][128 * 32];
  int tx = threadIdx.x;
  int lane = tx & 63;
  int orig = blockIdx.x + (blockIdx.y << 3) + (blockIdx.z << 7);
  int wgid = (orig & 7) * 32 + (orig >> 3);  // nwg=256, q=32
  int z = wgid >> 7;
  int rem = wgid & 127;
  int colStart = (rem & 7) * 128;
  int rowStart = (rem >> 3) * 256;
  const char* A0 = (const char*)(A + (size_t)rowStart * D_);
  const char* B0 = (const char*)(Bt + (size_t)colStart * D_);
  float* C = P + (size_t)z * MD_;
  int wave = tx >> 6, wm = wave >> 1, wn = wave & 1;
  int kbase = z * (D_ / 2);
  auto stage = [&](int buf, int k0) {  // exactly 6 gload_lds per thread
#pragma unroll
    for (int i = 0; i < 2; i++) {
      int c = i * 512 + tx;
      int row = c >> 2;
      int kb = swz(row, c & 3) * 16;
      size_t go = (size_t)row * (D_ * 2) + (size_t)k0 * 2 + kb;
      size_t lo = (size_t)(i * 512 + (tx & ~63)) * 16;
      gload_lds16(A0 + go, (char*)Ah[buf] + lo);
      gload_lds16(A0 + MD_ * 2 + go, (char*)Al[buf] + lo);
    }
    {
      int row = tx >> 2;
      int kb = swz(row, tx & 3) * 16;
      size_t go = (size_t)row * (D_ * 2) + (size_t)k0 * 2 + kb;
      size_t lo = (size_t)(tx & ~63) * 16;
      gload_lds16(B0 + go, (char*)Bh[buf] + lo);
      gload_lds16(B0 + DD_ * 2 + go, (char*)Bl[buf] + lo);
    }
  };
  f32x4 acc[4][4] = {};
  constexpr int NS = 16;  // (D_/2)/32
  int cur = 0;
  stage(0, kbase);
  for (int s = 0; s < NS; s++) {
    if (s + 1 < NS) {
      stage(cur ^ 1, kbase + (s + 1) * 32);
      asm volatile("s_waitcnt vmcnt(6)" ::: "memory");  // oldest 6 = cur buf
    } else {
      asm volatile("s_waitcnt vmcnt(0)" ::: "memory");
    }
    __builtin_amdgcn_s_barrier();
    short8 a[4], a2[4], b[4], b2[4];
#pragma unroll
    for (int m = 0; m < 4; m++) {
      int rr_ = wm * 64 + m * 16 + (lane & 15);
      int ro = rr_ * 32 + swz(rr_, lane >> 4) * 8;
      a[m] = *(const short8*)(Ah[cur] + ro);
      a2[m] = *(const short8*)(Al[cur] + ro);
    }
#pragma unroll
    for (int n = 0; n < 4; n++) {
      int rr_ = wn * 64 + n * 16 + (lane & 15);
      int ro = rr_ * 32 + swz(rr_, lane >> 4) * 8;
      b[n] = *(const short8*)(Bh[cur] + ro);
      b2[n] = *(const short8*)(Bl[cur] + ro);
    }
    __builtin_amdgcn_s_setprio(1);
#pragma unroll
    for (int m = 0; m < 4; m++)
#pragma unroll
      for (int n = 0; n < 4; n++) {
        acc[m][n] = MFMA(a[m], b[n], acc[m][n]);
        acc[m][n] = MFMA(a2[m], b[n], acc[m][n]);
        acc[m][n] = MFMA(a[m], b2[n], acc[m][n]);
      }
    __builtin_amdgcn_s_setprio(0);
    asm volatile("" ::: "memory");
    __builtin_amdgcn_s_barrier();
    cur ^= 1;
  }
  int r0 = rowStart + wm * 64 + ((lane >> 4) << 2);
  int cgl = colStart + wn * 64 + (lane & 15);
#pragma unroll
  for (int m = 0; m < 4; m++)
#pragma unroll
    for (int n = 0; n < 4; n++)
#pragma unroll
      for (int j = 0; j < 4; j++)
        C[(size_t)(r0 + m * 16 + j) * D_ + cgl + n * 16] = acc[m][n][j];
}

// ---- expert h GEMM: h = relu^2(Ak @ eWkT). 2-phase counted-vmcnt pipeline ----
__global__ __launch_bounds__(512) void gemm_exA(const short* __restrict__ A,
                                                const short* __restrict__ Bt,
                                                short* __restrict__ C,
                                                const int* __restrict__ offs) {
  __shared__ __align__(16) short As[2][256 * 32];
  __shared__ __align__(16) short Bs[2][128 * 32];
  int tx = threadIdx.x;
  int lane = tx & 63;
  int orig = blockIdx.x + (blockIdx.y << 4);
  int wgid = (orig & 7) * 80 + (orig >> 3);  // nwg=640, q=80
  int colStart = (wgid & 15) * 128;
  int rowStart = (wgid >> 4) * 256;
  if (rowStart >= offs[8]) return;
  int e = 0;
  while (e < 7 && rowStart >= offs[e + 1]) e++;
  const char* Ag = (const char*)(A + (size_t)rowStart * D_);
  const char* Bg = (const char*)(Bt + (size_t)e * F_ * D_ + (size_t)colStart * D_);
  int wave = tx >> 6, wm = wave >> 1, wn = wave & 1;
  auto stage = [&](int buf, int s) {  // 3 gload_lds per thread, exactly
    size_t kb2 = (size_t)s << 6;
#pragma unroll
    for (int i = 0; i < 2; i++) {
      int c = i * 512 + tx;
      int row = c >> 2;
      int kb = swz(row, c & 3) * 16;
      gload_lds16(Ag + (size_t)row * (D_ * 2) + kb2 + kb,
                  (char*)As[buf] + (size_t)(i * 512 + (tx & ~63)) * 16);
    }
    {
      int row = tx >> 2;
      int kb = swz(row, tx & 3) * 16;
      gload_lds16(Bg + (size_t)row * (D_ * 2) + kb2 + kb,
                  (char*)Bs[buf] + (size_t)(tx & ~63) * 16);
    }
  };
  f32x4 acc[4][4] = {};
  constexpr int NS = 32;
  int cur = 0;
  stage(0, 0);
  for (int s = 0; s < NS; s++) {
    if (s + 1 < NS) {
      stage(cur ^ 1, s + 1);
      asm volatile("s_waitcnt vmcnt(3)" ::: "memory");  // oldest 3 = cur buf
    } else {
      asm volatile("s_waitcnt vmcnt(0)" ::: "memory");
    }
    __builtin_amdgcn_s_barrier();  // all waves' cur-buf writes landed
    short8 a[4], b[4];
#pragma unroll
    for (int m = 0; m < 4; m++) {
      int rr_ = wm * 64 + m * 16 + (lane & 15);
      a[m] = *(const short8*)(As[cur] + rr_ * 32 + swz(rr_, lane >> 4) * 8);
    }
#pragma unroll
    for (int n = 0; n < 4; n++) {
      int rr_ = wn * 64 + n * 16 + (lane & 15);
      b[n] = *(const short8*)(Bs[cur] + rr_ * 32 + swz(rr_, lane >> 4) * 8);
    }
    __builtin_amdgcn_s_setprio(1);
#pragma unroll
    for (int m = 0; m < 4; m++)
#pragma unroll
      for (int n = 0; n < 4; n++) acc[m][n] = MFMA(a[m], b[n], acc[m][n]);
    __builtin_amdgcn_s_setprio(0);
    asm volatile("" ::: "memory");
    __builtin_amdgcn_s_barrier();  // all reads of cur done before overwrite
    cur ^= 1;
  }
  int r0 = rowStart + wm * 64 + ((lane >> 4) << 2);
  int cgl = colStart + wn * 64 + (lane & 15);
#pragma unroll
  for (int m = 0; m < 4; m++)
#pragma unroll
    for (int n = 0; n < 4; n++)
#pragma unroll
      for (int j = 0; j < 4; j++) {
        size_t idx = (size_t)(r0 + m * 16 + j) * F_ + cgl + n * 16;
        float vv = acc[m][n][j];
        vv = vv > 0.f ? vv * vv : 0.f;
        C[idx] = f2bf(vv);
      }
}

// ---- merged expert GEMMs (2-phase counted-vmcnt): z=0 kvb=h@eWvT; z=1 rrb ----
__global__ __launch_bounds__(512) void gemm_ex2(
    const short* __restrict__ h, const short* __restrict__ eWvT,
    short* __restrict__ kvb, const short* __restrict__ Ar,
    const short* __restrict__ eWrT, short* __restrict__ rrb,
    const int* __restrict__ offs) {
  __shared__ __align__(16) short As[2][256 * 32];
  __shared__ __align__(16) short Bs[2][128 * 32];
  int tx = threadIdx.x;
  int lane = tx & 63;
  int zz = blockIdx.z;
  int orig = blockIdx.x + (blockIdx.y << 3);
  int wgid = (orig & 7) * 40 + (orig >> 3);  // per-slice nwg=320, q=40
  int colStart = (wgid & 7) * 128;
  int rowStart = (wgid >> 3) * 256;
  if (rowStart >= offs[8]) return;
  int e = 0;
  while (e < 7 && rowStart >= offs[e + 1]) e++;
  int K = zz ? D_ : F_;
  const char* Ag = (const char*)((zz ? Ar : h) + (size_t)rowStart * K);
  const char* Bg =
      (const char*)((zz ? eWrT : eWvT) + (size_t)e * D_ * K + (size_t)colStart * K);
  int wave = tx >> 6, wm = wave >> 1, wn = wave & 1;
  const int NS = K / 32;
  auto stage = [&](int buf, int s) {  // 3 gload_lds per thread, exactly
    size_t kb2 = (size_t)s << 6;
#pragma unroll
    for (int i = 0; i < 2; i++) {
      int c = i * 512 + tx;
      int row = c >> 2;
      int kb = swz(row, c & 3) * 16;
      gload_lds16(Ag + (size_t)row * ((size_t)K * 2) + kb2 + kb,
                  (char*)As[buf] + (size_t)(i * 512 + (tx & ~63)) * 16);
    }
    {
      int row = tx >> 2;
      int kb = swz(row, tx & 3) * 16;
      gload_lds16(Bg + (size_t)row * ((size_t)K * 2) + kb2 + kb,
                  (char*)Bs[buf] + (size_t)(tx & ~63) * 16);
    }
  };
  f32x4 acc[4][4] = {};
  int cur = 0;
  stage(0, 0);
  for (int s = 0; s < NS; s++) {
    if (s + 1 < NS) {
      stage(cur ^ 1, s + 1);
      asm volatile("s_waitcnt vmcnt(3)" ::: "memory");
    } else {
      asm volatile("s_waitcnt vmcnt(0)" ::: "memory");
    }
    __builtin_amdgcn_s_barrier();
    short8 a[4], b[4];
#pragma unroll
    for (int m = 0; m < 4; m++) {
      int rr_ = wm * 64 + m * 16 + (lane & 15);
      a[m] = *(const short8*)(As[cur] + rr_ * 32 + swz(rr_, lane >> 4) * 8);
    }
#pragma unroll
    for (int n = 0; n < 4; n++) {
      int rr_ = wn * 64 + n * 16 + (lane & 15);
      b[n] = *(const short8*)(Bs[cur] + rr_ * 32 + swz(rr_, lane >> 4) * 8);
    }
    __builtin_amdgcn_s_setprio(1);
#pragma unroll
    for (int m = 0; m < 4; m++)
#pragma unroll
      for (int n = 0; n < 4; n++) acc[m][n] = MFMA(a[m], b[n], acc[m][n]);
    __builtin_amdgcn_s_setprio(0);
    asm volatile("" ::: "memory");
    __builtin_amdgcn_s_barrier();
    cur ^= 1;
  }
  short* C = zz ? rrb : kvb;
  int r0 = rowStart + wm * 64 + ((lane >> 4) << 2);
  int cgl = colStart + wn * 64 + (lane & 15);
#pragma unroll
  for (int m = 0; m < 4; m++)
#pragma unroll
    for (int n = 0; n < 4; n++)
#pragma unroll
      for (int j = 0; j < 4; j++) {
        size_t idx = (size_t)(r0 + m * 16 + j) * D_ + cgl + n * 16;
        float vv = acc[m][n][j];
        if (zz) vv = 1.0f / (1.0f + __expf(-vv));
        C[idx] = f2bf(vv);
      }
}

// ---------------- WKV chunked scan ----------------
__global__ __launch_bounds__(256) void wkv_chunk_kernel(const float* __restrict__ k,
                                                        const float* __restrict__ v,
                                                        const float* __restrict__ td,
                                                        float* __restrict__ chA,
                                                        float* __restrict__ chB) {
  int d = blockIdx.x * 256 + threadIdx.x;
  int c = blockIdx.y;
  int b = blockIdx.z;
  float w = -__expf(td[d]);
  float dec = __expf(w);
  float A = 0.f, Bb = 0.f;
  size_t base = ((size_t)b * S_ + (size_t)c * L_) * D_ + d;
  for (int i = 0; i < L_; i++) {
    float kt = k[base + (size_t)i * D_];
    float vt = v[base + (size_t)i * D_];
    float ek = __expf(kt);
    A = fmaf(A, dec, ek * vt);
    Bb = fmaf(Bb, dec, ek);
  }
  size_t o = ((size_t)b * NC_ + c) * D_ + d;
  chA[o] = A;
  chB[o] = Bb;
}

__global__ __launch_bounds__(256) void wkv_carry_kernel(const float* __restrict__ chA,
                                                        const float* __restrict__ chB,
                                                        const float* __restrict__ td,
                                                        float* __restrict__ caA,
                                                        float* __restrict__ caB) {
  int d = blockIdx.x * 256 + threadIdx.x;
  int b = blockIdx.y;
  float w = -__expf(td[d]);
  float decL = __expf(w * (float)L_);
  float A = 0.f, Bb = 0.f;
  for (int c = 0; c < NC_; c++) {
    size_t o = ((size_t)b * NC_ + c) * D_ + d;
    caA[o] = A;
    caB[o] = Bb;
    A = fmaf(A, decL, chA[o]);
    Bb = fmaf(Bb, decL, chB[o]);
  }
}

__global__ __launch_bounds__(256) void wkv_out_kernel(
    const float* __restrict__ k, const float* __restrict__ v,
    const float* __restrict__ r, const float* __restrict__ caA,
    const float* __restrict__ caB, const float* __restrict__ td,
    const float* __restrict__ tf, short* __restrict__ rwkv) {
  int d = blockIdx.x * 256 + threadIdx.x;
  int c = blockIdx.y;
  int b = blockIdx.z;
  float w = -__expf(td[d]);
  float dec = __expf(w);
  float eu = __expf(tf[d]);
  size_t co = ((size_t)b * NC_ + c) * D_ + d;
  float A = caA[co], Bb = caB[co];
  size_t base = ((size_t)b * S_ + (size_t)c * L_) * D_ + d;
  for (int i = 0; i < L_; i++) {
    size_t ix = base + (size_t)i * D_;
    float kt = k[ix], vt = v[ix], rt = r[ix];
    float ek = __expf(kt);
    float euk = eu * ek;
    float wkv = (A + euk * vt) / (Bb + euk);
    BfPair p = split2(rt * wkv);
    rwkv[ix] = p.hi;
    rwkv[MD_ + ix] = p.lo;
    A = fmaf(A, dec, ek * vt);
    Bb = fmaf(Bb, dec, ek);
  }
}

// ---------------- MoE gather + channel-mix (build Ak/Ar, bf16) ----------------
__global__ __launch_bounds__(256) void gather_mix_kernel(
    const float* __restrict__ ei, const float* __restrict__ cmk,
    const float* __restrict__ cmr, const int* __restrict__ offs,
    const int* __restrict__ counts, const int* __restrict__ elist,
    short* __restrict__ Ak, short* __restrict__ Ar) {
  int row = blockIdx.x;
  if (row >= offs[8]) return;
  int e = 0;
  while (e < 7 && row >= offs[e + 1]) e++;
  int p = row - offs[e];
  int d = threadIdx.x * 4;
  size_t ro = (size_t)row * D_ + d;
  if (p >= counts[e]) {
    s16x4 z = {0, 0, 0, 0};
    *(s16x4*)(Ak + ro) = z;
    *(s16x4*)(Ar + ro) = z;
    return;
  }
  int t = elist[row];
  int s = t & (S_ - 1);
  f32x4 cur = *(const f32x4*)(ei + (size_t)t * D_ + d);
  f32x4 prev = {0.f, 0.f, 0.f, 0.f};
  if (s > 0) prev = *(const f32x4*)(ei + (size_t)(t - 1) * D_ + d);
  f32x4 mk = *(const f32x4*)(cmk + (size_t)e * D_ + d);
  f32x4 mr = *(const f32x4*)(cmr + (size_t)e * D_ + d);
  s16x4 ok, orr;
#pragma unroll
  for (int j = 0; j < 4; j++) {
    ok[j] = f2bf(cur[j] * mk[j] + prev[j] * (1.f - mk[j]));
    orr[j] = f2bf(cur[j] * mr[j] + prev[j] * (1.f - mr[j]));
  }
  *(s16x4*)(Ak + ro) = ok;
  *(s16x4*)(Ar + ro) = orr;
}

// ---------------- final: out = xout + sum_j w_j * rr * kv ----------------
__global__ __launch_bounds__(256) void final_kernel(
    const float* __restrict__ xout, const short* __restrict__ rrb,
    const short* __restrict__ kvb, const int* __restrict__ slots,
    const float* __restrict__ wts2, float* __restrict__ out) {
  size_t i4 = (size_t)blockIdx.x * 256 + threadIdx.x;
  size_t el = i4 * 4;
  int t = (int)(el >> 10);
  int d = (int)(el & (D_ - 1));
  int s0 = slots[t * 2], s1 = slots[t * 2 + 1];
  float w0 = wts2[t * 2], w1 = wts2[t * 2 + 1];
  f32x4 xo = *(const f32x4*)(xout + el);
  s16x4 r0 = *(const s16x4*)(rrb + (size_t)s0 * D_ + d);
  s16x4 k0 = *(const s16x4*)(kvb + (size_t)s0 * D_ + d);
  s16x4 r1 = *(const s16x4*)(rrb + (size_t)s1 * D_ + d);
  s16x4 k1 = *(const s16x4*)(kvb + (size_t)s1 * D_ + d);
  f32x4 o;
#pragma unroll
  for (int j = 0; j < 4; j++)
    o[j] = xo[j] + w0 * bf2f(r0[j]) * bf2f(k0[j]) + w1 * bf2f(r1[j]) * bf2f(k1[j]);
  *(f32x4*)(out + el) = o;
}

// ============================================================================
extern "C" void kernel_launch(void* const* d_in, const int* in_sizes, int n_in,
                              void* d_out, int out_size, void* d_ws, size_t ws_size,
                              hipStream_t stream) {
  (void)in_sizes; (void)n_in; (void)out_size; (void)ws_size;
  const float* x = (const float*)d_in[0];
  const float* ln1g = (const float*)d_in[1];
  const float* ln1b = (const float*)d_in[2];
  const float* ln2g = (const float*)d_in[3];
  const float* ln2b = (const float*)d_in[4];
  const float* muk = (const float*)d_in[5];
  const float* muv = (const float*)d_in[6];
  const float* mur = (const float*)d_in[7];
  const float* tdec = (const float*)d_in[8];
  const float* tfirst = (const float*)d_in[9];
  const float* Wk = (const float*)d_in[10];
  const float* Wv = (const float*)d_in[11];
  const float* Wr = (const float*)d_in[12];
  const float* Wo = (const float*)d_in[13];
  const float* rw = (const float*)d_in[14];
  const float* cmk = (const float*)d_in[15];
  const float* cmr = (const float*)d_in[16];
  const float* eWk = (const float*)d_in[17];
  const float* eWv = (const float*)d_in[18];
  const float* eWr = (const float*)d_in[19];
  float* out = (float*)d_out;

  char* w = (char*)d_ws;
  size_t off = 0;
  auto alloc = [&](size_t bytes) {
    size_t o = off;
    off = (off + bytes + 255) & ~(size_t)255;
    return o;
  };
  const size_t szDD2x2 = DD_ * 2 * 2;
  size_t o_WT = alloc(4 * szDD2x2);
  size_t o_WkT = o_WT, o_WoT = o_WT + 3 * szDD2x2;
  size_t o_eWkT = alloc((size_t)E_ * D_ * F_ * 2);
  size_t o_eWvT = alloc((size_t)E_ * F_ * D_ * 2);
  size_t o_eWrT = alloc((size_t)E_ * D_ * D_ * 2);
  size_t o_xout = alloc(MD_ * 4);
  size_t o_ei = alloc(MD_ * 4);
  size_t o_counts = alloc(64);
  size_t o_offs = alloc(64);
  size_t o_idx2 = alloc((size_t)M_ * 2 * 4);
  size_t o_wts2 = alloc((size_t)M_ * 2 * 4);
  size_t o_pos2 = alloc((size_t)M_ * 2 * 4);
  size_t o_blockcnt = alloc((size_t)HB_ * 8 * 4);
  size_t o_gbase = alloc((size_t)HB_ * 8 * 4);
  size_t o_elist = alloc((size_t)PC_ * 4);
  size_t o_slots = alloc((size_t)M_ * 2 * 4);
  size_t poolBase = off;
  size_t off1 = poolBase;
  auto alloc1 = [&](size_t bytes) {
    size_t o = off1;
    off1 = (off1 + bytes + 255) & ~(size_t)255;
    return o;
  };
  size_t o_rwkv = alloc1(MD_ * 2 * 2);
  size_t o_xk = alloc1(MD_ * 2 * 2);
  size_t o_xv = alloc1(MD_ * 2 * 2);
  size_t o_xr = alloc1(MD_ * 2 * 2);
  size_t o_k = alloc1(MD_ * 4);
  size_t o_v = alloc1(MD_ * 4);
  size_t o_r = alloc1(MD_ * 4);
  size_t o_chA = alloc1((size_t)B_ * NC_ * D_ * 4);
  size_t o_chB = alloc1((size_t)B_ * NC_ * D_ * 4);
  size_t o_caA = alloc1((size_t)B_ * NC_ * D_ * 4);
  size_t o_caB = alloc1((size_t)B_ * NC_ * D_ * 4);
  size_t o_P = o_k;  // alias: k/v dead after wkv_out
  size_t off2 = poolBase;
  auto alloc2 = [&](size_t bytes) {
    size_t o = off2;
    off2 = (off2 + bytes + 255) & ~(size_t)255;
    return o;
  };
  size_t o_Ak = alloc2((size_t)PC_ * D_ * 2);
  size_t o_Ar = alloc2((size_t)PC_ * D_ * 2);
  size_t o_h = alloc2((size_t)PC_ * F_ * 2);
  size_t o_kvb = alloc2((size_t)PC_ * D_ * 2);
  size_t o_rrb = alloc2((size_t)PC_ * D_ * 2);

#define WP(T, o) ((T*)(w + (o)))

  transpose_cvt4<<<dim3(32, 32, 4), 256, 0, stream>>>(Wk, Wv, Wr, Wo,
                                                      WP(short, o_WkT));
  transpose_cvt<0><<<dim3(F_ / 32, D_ / 32, E_), 256, 0, stream>>>(eWk, WP(short, o_eWkT), D_, F_);
  transpose_cvt<0><<<dim3(D_ / 32, F_ / 32, E_), 256, 0, stream>>>(eWv, WP(short, o_eWvT), F_, D_);
  transpose_cvt<0><<<dim3(D_ / 32, D_ / 32, E_), 256, 0, stream>>>(eWr, WP(short, o_eWrT), D_, D_);

  lnmix_kernel<<<M_, 256, 0, stream>>>(x, ln1g, ln1b, muk, muv, mur,
                                       WP(short, o_xk), WP(short, o_xv),
                                       WP(short, o_xr));

  gemm_kvr<<<dim3(8, 16, 3), 512, 0, stream>>>(WP(short, o_xk), WP(short, o_WkT),
                                               WP(float, o_k));

  wkv_chunk_kernel<<<dim3(D_ / 256, NC_, B_), 256, 0, stream>>>(
      WP(float, o_k), WP(float, o_v), tdec, WP(float, o_chA), WP(float, o_chB));
  wkv_carry_kernel<<<dim3(D_ / 256, B_), 256, 0, stream>>>(
      WP(float, o_chA), WP(float, o_chB), tdec, WP(float, o_caA), WP(float, o_caB));
  wkv_out_kernel<<<dim3(D_ / 256, NC_, B_), 256, 0, stream>>>(
      WP(float, o_k), WP(float, o_v), WP(float, o_r), WP(float, o_caA),
      WP(float, o_caB), tdec, tfirst, WP(short, o_rwkv));

  gemm_wo<<<dim3(8, 16, 2), 512, 0, stream>>>(WP(short, o_rwkv), WP(short, o_WoT),
                                              WP(float, o_P));
  ln2_router<<<M_, 256, 0, stream>>>(x, WP(float, o_P), ln2g, ln2b, rw,
                                     WP(float, o_xout), WP(float, o_ei),
                                     WP(int, o_idx2), WP(float, o_wts2));

  hist_kernel<<<HB_, 512, 0, stream>>>(WP(int, o_idx2), WP(int, o_pos2),
                                       WP(int, o_blockcnt));
  scan_kernel<<<1, 128, 0, stream>>>(WP(int, o_blockcnt), WP(int, o_offs),
                                     WP(int, o_counts), WP(int, o_gbase));
  slot_kernel<<<(2 * M_) / 256, 256, 0, stream>>>(WP(int, o_idx2), WP(int, o_pos2),
                                                  WP(int, o_gbase), WP(int, o_elist),
                                                  WP(int, o_slots));
  gather_mix_kernel<<<PC_, 256, 0, stream>>>(WP(float, o_ei), cmk, cmr, WP(int, o_offs),
                                             WP(int, o_counts), WP(int, o_elist),
                                             WP(short, o_Ak), WP(short, o_Ar));

  gemm_exA<<<dim3(16, 40), 512, 0, stream>>>(WP(short, o_Ak), WP(short, o_eWkT),
                                             WP(short, o_h), WP(int, o_offs));
  gemm_ex2<<<dim3(8, 40, 2), 512, 0, stream>>>(
      WP(short, o_h), WP(short, o_eWvT), WP(short, o_kvb), WP(short, o_Ar),
      WP(short, o_eWrT), WP(short, o_rrb), WP(int, o_offs));

  final_kernel<<<M_ * D_ / 4 / 256, 256, 0, stream>>>(
      WP(float, o_xout), WP(short, o_rrb), WP(short, o_kvb), WP(int, o_slots),
      WP(float, o_wts2), out);
#undef WP
}

// Round 18
// 432.246 us; speedup vs baseline: 1.0748x; 1.0020x over previous
//
#include <hip/hip_runtime.h>
#include <hip/hip_bf16.h>
#include <stdint.h>

#define DEVI __device__ __forceinline__

typedef __attribute__((ext_vector_type(4))) float f32x4;
typedef __attribute__((ext_vector_type(8))) short short8;
typedef __attribute__((ext_vector_type(4))) short s16x4;

constexpr int B_ = 2, S_ = 2048, D_ = 1024, E_ = 8, F_ = 2048;
constexpr int M_ = B_ * S_;        // 4096 tokens
constexpr int PC_ = 10240;         // padded pair capacity (8192 + 8*256)
constexpr int NC_ = 64, L_ = 32;   // scan chunking: NC_*L_ == S_
constexpr int HB_ = 16;            // hist blocks (HB_*512 == 2*M_)
constexpr size_t MD_ = (size_t)M_ * D_;
constexpr size_t DD_ = (size_t)D_ * D_;

DEVI short f2bf(float f) {
  uint32_t u = __float_as_uint(f);
  u = (u + 0x7fffu + ((u >> 16) & 1u)) >> 16;
  return (short)u;
}
DEVI float bf2f(short s) { return __uint_as_float(((uint32_t)(uint16_t)s) << 16); }
struct BfPair { short hi, lo; };
DEVI BfPair split2(float f) {
  BfPair p;
  p.hi = f2bf(f);
  p.lo = f2bf(f - bf2f(p.hi));
  return p;
}

DEVI void gload_lds16(const void* g, void* l) {
  __builtin_amdgcn_global_load_lds(
      (const __attribute__((address_space(1))) unsigned int*)g,
      (__attribute__((address_space(3))) unsigned int*)l, 16, 0, 0);
}

// bank-conflict swizzle: 16B-slot XOR within a 64B row (involution; applied
// to the global SOURCE slot at stage time and to the READ slot — LDS dest
// stays linear as required by global_load_lds).
DEVI int swz(int row, int slot) { return slot ^ ((row >> 1) & 3); }

#define MFMA(a, b, c) __builtin_amdgcn_mfma_f32_16x16x32_bf16((a), (b), (c), 0, 0, 0)

// ---- fused LN1 + time-mix ----
__global__ __launch_bounds__(256) void lnmix_kernel(
    const float* __restrict__ x, const float* __restrict__ g,
    const float* __restrict__ b, const float* __restrict__ muk,
    const float* __restrict__ muv, const float* __restrict__ mur,
    short* __restrict__ xk, short* __restrict__ xv, short* __restrict__ xr) {
  int row = blockIdx.x;
  int tx = threadIdx.x;
  int s = row & (S_ - 1);
  size_t o = (size_t)row * D_ + tx * 4;
  f32x4 cur = *(const f32x4*)(x + o);
  f32x4 prv = {0.f, 0.f, 0.f, 0.f};
  if (s > 0) prv = *(const f32x4*)(x + o - D_);
  float a0 = cur[0] + cur[1] + cur[2] + cur[3];
  float a1 = cur[0] * cur[0] + cur[1] * cur[1] + cur[2] * cur[2] + cur[3] * cur[3];
  float a2 = prv[0] + prv[1] + prv[2] + prv[3];
  float a3 = prv[0] * prv[0] + prv[1] * prv[1] + prv[2] * prv[2] + prv[3] * prv[3];
#pragma unroll
  for (int o2 = 32; o2; o2 >>= 1) {
    a0 += __shfl_down(a0, o2);
    a1 += __shfl_down(a1, o2);
    a2 += __shfl_down(a2, o2);
    a3 += __shfl_down(a3, o2);
  }
  __shared__ float rd[4][4];
  if ((tx & 63) == 0) {
    rd[tx >> 6][0] = a0; rd[tx >> 6][1] = a1;
    rd[tx >> 6][2] = a2; rd[tx >> 6][3] = a3;
  }
  __syncthreads();
  a0 = rd[0][0] + rd[1][0] + rd[2][0] + rd[3][0];
  a1 = rd[0][1] + rd[1][1] + rd[2][1] + rd[3][1];
  a2 = rd[0][2] + rd[1][2] + rd[2][2] + rd[3][2];
  a3 = rd[0][3] + rd[1][3] + rd[2][3] + rd[3][3];
  float mc = a0 * (1.0f / D_);
  float rc = rsqrtf(a1 * (1.0f / D_) - mc * mc + 1e-5f);
  float mp = a2 * (1.0f / D_);
  float rp = rsqrtf(a3 * (1.0f / D_) - mp * mp + 1e-5f);
  int d = tx * 4;
  f32x4 gg = *(const f32x4*)(g + d);
  f32x4 bb = *(const f32x4*)(b + d);
  f32x4 mk = *(const f32x4*)(muk + d);
  f32x4 mv = *(const f32x4*)(muv + d);
  f32x4 mr = *(const f32x4*)(mur + d);
  s16x4 okh, okl, ovh, ovl, orh, orl;
#pragma unroll
  for (int j = 0; j < 4; j++) {
    float c = (cur[j] - mc) * rc * gg[j] + bb[j];
    float p = (s > 0) ? (prv[j] - mp) * rp * gg[j] + bb[j] : 0.f;
    BfPair pk = split2(c * mk[j] + p * (1.f - mk[j]));
    BfPair pv = split2(c * mv[j] + p * (1.f - mv[j]));
    BfPair pr = split2(c * mr[j] + p * (1.f - mr[j]));
    okh[j] = pk.hi; okl[j] = pk.lo;
    ovh[j] = pv.hi; ovl[j] = pv.lo;
    orh[j] = pr.hi; orl[j] = pr.lo;
  }
  *(s16x4*)(xk + o) = okh;
  *(s16x4*)(xk + MD_ + o) = okl;
  *(s16x4*)(xv + o) = ovh;
  *(s16x4*)(xv + MD_ + o) = ovl;
  *(s16x4*)(xr + o) = orh;
  *(s16x4*)(xr + MD_ + o) = orl;
}

// ---- fused: xout = x + P0+P1; ei = LN(xout); router logits+top2 (NO atomics)
__global__ __launch_bounds__(256) void ln2_router(
    const float* __restrict__ x, const float* __restrict__ P,
    const float* __restrict__ g, const float* __restrict__ b,
    const float* __restrict__ rw, float* __restrict__ xout,
    float* __restrict__ ei, int* __restrict__ idx2, float* __restrict__ wts2) {
  int row = blockIdx.x;
  int tx = threadIdx.x;
  size_t o = (size_t)row * D_ + tx * 4;
  f32x4 v = *(const f32x4*)(x + o);
  f32x4 p0 = *(const f32x4*)(P + o);
  f32x4 p1 = *(const f32x4*)(P + MD_ + o);
#pragma unroll
  for (int j = 0; j < 4; j++) v[j] += p0[j] + p1[j];
  *(f32x4*)(xout + o) = v;
  float s = v[0] + v[1] + v[2] + v[3];
  float s2 = v[0] * v[0] + v[1] * v[1] + v[2] * v[2] + v[3] * v[3];
#pragma unroll
  for (int of = 32; of; of >>= 1) {
    s += __shfl_down(s, of);
    s2 += __shfl_down(s2, of);
  }
  __shared__ float w1[4], w2[4];
  if ((tx & 63) == 0) { w1[tx >> 6] = s; w2[tx >> 6] = s2; }
  __syncthreads();
  s = w1[0] + w1[1] + w1[2] + w1[3];
  s2 = w2[0] + w2[1] + w2[2] + w2[3];
  float mean = s * (1.0f / D_);
  float rstd = rsqrtf(s2 * (1.0f / D_) - mean * mean + 1e-5f);
  f32x4 gg = *(const f32x4*)(g + tx * 4);
  f32x4 bb = *(const f32x4*)(b + tx * 4);
  f32x4 oo;
#pragma unroll
  for (int j = 0; j < 4; j++) oo[j] = (v[j] - mean) * rstd * gg[j] + bb[j];
  *(f32x4*)(ei + o) = oo;
  float pl[8] = {};
  const float* rr = rw + (size_t)(tx * 4) * 8;
#pragma unroll
  for (int j = 0; j < 4; j++)
#pragma unroll
    for (int e = 0; e < 8; e++) pl[e] += oo[j] * rr[j * 8 + e];
#pragma unroll
  for (int of = 32; of; of >>= 1)
#pragma unroll
    for (int e = 0; e < 8; e++) pl[e] += __shfl_down(pl[e], of);
  __shared__ float plw[4][8];
  if ((tx & 63) == 0)
#pragma unroll
    for (int e = 0; e < 8; e++) plw[tx >> 6][e] = pl[e];
  __syncthreads();
  if (tx == 0) {
    float p8[8];
#pragma unroll
    for (int e = 0; e < 8; e++)
      p8[e] = plw[0][e] + plw[1][e] + plw[2][e] + plw[3][e];
    float mx = p8[0];
#pragma unroll
    for (int e = 1; e < 8; e++) mx = fmaxf(mx, p8[e]);
    float pr[8];
#pragma unroll
    for (int e = 0; e < 8; e++) pr[e] = __expf(p8[e] - mx);
    int i1 = 0;
#pragma unroll
    for (int e = 1; e < 8; e++)
      if (pr[e] > pr[i1]) i1 = e;
    int i2 = (i1 == 0) ? 1 : 0;
#pragma unroll
    for (int e = 0; e < 8; e++)
      if (e != i1 && pr[e] > pr[i2]) i2 = e;
    float v1 = pr[i1], v2 = pr[i2];
    float inv = 1.f / (v1 + v2);
    int t = row;
    idx2[t * 2] = i1;
    idx2[t * 2 + 1] = i2;
    wts2[t * 2] = v1 * inv;
    wts2[t * 2 + 1] = v2 * inv;
  }
}

// ---- per-block expert histogram via LDS atomics ----
__global__ __launch_bounds__(512) void hist_kernel(const int* __restrict__ idx2,
                                                   int* __restrict__ pos2,
                                                   int* __restrict__ blockcnt) {
  __shared__ int cnt[8];
  int tx = threadIdx.x;
  if (tx < 8) cnt[tx] = 0;
  __syncthreads();
  int entry = blockIdx.x * 512 + tx;
  int e = idx2[entry];
  pos2[entry] = atomicAdd(&cnt[e], 1);
  __syncthreads();
  if (tx < 8) blockcnt[blockIdx.x * 8 + tx] = cnt[tx];
}

// ---- scan: per-expert prefix over block counts; padded expert offsets ----
__global__ __launch_bounds__(128) void scan_kernel(const int* __restrict__ blockcnt,
                                                   int* __restrict__ offs,
                                                   int* __restrict__ counts,
                                                   int* __restrict__ gbase) {
  __shared__ int c[HB_][8];
  __shared__ int tot[8];
  __shared__ int eoff[9];
  int tx = threadIdx.x;
  c[tx >> 3][tx & 7] = blockcnt[tx];
  __syncthreads();
  if (tx < 8) {
    int s = 0;
    for (int b2 = 0; b2 < HB_; b2++) {
      int v = c[b2][tx];
      c[b2][tx] = s;
      s += v;
    }
    tot[tx] = s;
    counts[tx] = s;
  }
  __syncthreads();
  if (tx == 0) {
    int o = 0;
    for (int e = 0; e < 8; e++) {
      eoff[e] = o;
      o += ((tot[e] + 255) >> 8) << 8;
    }
    eoff[8] = o;
    for (int e = 0; e < 9; e++) offs[e] = eoff[e];
  }
  __syncthreads();
  gbase[tx] = eoff[tx & 7] + c[tx >> 3][tx & 7];
}

// ---- slots: pure loads ----
__global__ __launch_bounds__(256) void slot_kernel(const int* __restrict__ idx2,
                                                   const int* __restrict__ pos2,
                                                   const int* __restrict__ gbase,
                                                   int* __restrict__ elist,
                                                   int* __restrict__ slots) {
  int entry = blockIdx.x * 256 + threadIdx.x;
  int e = idx2[entry];
  int slot = gbase[(entry >> 9) * 8 + e] + pos2[entry];
  elist[slot] = entry >> 1;
  slots[entry] = slot;
}

// ------- transpose (+cvt): in (R,C) -> out (C,R) -----
template <int SPLIT>
__global__ __launch_bounds__(256) void transpose_cvt(const float* __restrict__ in,
                                                     short* __restrict__ out, int R,
                                                     int C) {
  __shared__ float t[32][33];
  size_t PS = (size_t)R * C;
  const float* inm = in + (size_t)blockIdx.z * PS;
  short* outm = out + (size_t)blockIdx.z * PS * (SPLIT ? 2 : 1);
  int r = threadIdx.x >> 3;
  int c4 = (threadIdx.x & 7) * 4;
  f32x4 v = *(const f32x4*)(inm + (size_t)(blockIdx.y * 32 + r) * C + blockIdx.x * 32 + c4);
#pragma unroll
  for (int i = 0; i < 4; i++) t[r][c4 + i] = v[i];
  __syncthreads();
  s16x4 oh, ol;
#pragma unroll
  for (int i = 0; i < 4; i++) {
    float val = t[c4 + i][r];
    if (SPLIT) {
      BfPair p = split2(val);
      oh[i] = p.hi;
      ol[i] = p.lo;
    } else {
      oh[i] = f2bf(val);
    }
  }
  size_t oidx = (size_t)(blockIdx.x * 32 + r) * R + blockIdx.y * 32 + c4;
  *(s16x4*)(outm + oidx) = oh;
  if (SPLIT) *(s16x4*)(outm + PS + oidx) = ol;
}

// ---- 4 dense DxD weights in one launch; split planes out ----
__global__ __launch_bounds__(256) void transpose_cvt4(
    const float* __restrict__ w0, const float* __restrict__ w1,
    const float* __restrict__ w2, const float* __restrict__ w3,
    short* __restrict__ out) {
  __shared__ float t[32][33];
  int z = blockIdx.z;
  const float* inm = (z == 0) ? w0 : (z == 1) ? w1 : (z == 2) ? w2 : w3;
  short* outm = out + (size_t)z * (2 * DD_);
  int r = threadIdx.x >> 3;
  int c4 = (threadIdx.x & 7) * 4;
  f32x4 v = *(const f32x4*)(inm + (size_t)(blockIdx.y * 32 + r) * D_ + blockIdx.x * 32 + c4);
#pragma unroll
  for (int i = 0; i < 4; i++) t[r][c4 + i] = v[i];
  __syncthreads();
  s16x4 oh, ol;
#pragma unroll
  for (int i = 0; i < 4; i++) {
    BfPair p = split2(t[c4 + i][r]);
    oh[i] = p.hi;
    ol[i] = p.lo;
  }
  size_t oidx = (size_t)(blockIdx.x * 32 + r) * D_ + blockIdx.y * 32 + c4;
  *(s16x4*)(outm + oidx) = oh;
  *(s16x4*)(outm + DD_ + oidx) = ol;
}

// ======== 256x128 tile, 8 waves (4M x 2N), BK=32, swizzled LDS slots ========

// ---- batched k/v/r split GEMM (best body: 4-buffer, single-stage) ----
__global__ __launch_bounds__(512) void gemm_kvr(const short* __restrict__ X,
                                                const short* __restrict__ W,
                                                float* __restrict__ KVR) {
  __shared__ __align__(16) short Ah[256 * 32], Al[256 * 32];
  __shared__ __align__(16) short Bh[128 * 32], Bl[128 * 32];
  int tx = threadIdx.x;
  int lane = tx & 63;
  int orig = blockIdx.x + (blockIdx.y << 3) + (blockIdx.z << 7);
  int wgid = (orig & 7) * 48 + (orig >> 3);  // nwg=384, q=48
  int z = wgid >> 7;
  int rem = wgid & 127;
  int colStart = (rem & 7) * 128;
  int rowStart = (rem >> 3) * 256;
  const short* A0 = X + (size_t)z * (2 * MD_) + (size_t)rowStart * D_;
  const short* B0 = W + (size_t)z * (2 * DD_) + (size_t)colStart * D_;
  float* C = KVR + (size_t)z * MD_;
  int wave = tx >> 6, wm = wave >> 1, wn = wave & 1;
  f32x4 acc[4][4] = {};
  for (int k0 = 0; k0 < D_; k0 += 32) {
#pragma unroll
    for (int i = 0; i < 2; i++) {  // A planes: 2 chunks/thread each
      int c = i * 512 + tx;
      int row = c >> 2;
      int kb = swz(row, c & 3) * 16;
      size_t go = (size_t)row * (D_ * 2) + (size_t)k0 * 2 + kb;
      size_t lo = (size_t)(i * 512 + (tx & ~63)) * 16;
      gload_lds16((const char*)A0 + go, (char*)Ah + lo);
      gload_lds16((const char*)A0 + MD_ * 2 + go, (char*)Al + lo);
    }
    {  // B planes: 1 chunk/thread each
      int row = tx >> 2;
      int kb = swz(row, tx & 3) * 16;
      size_t go = (size_t)row * (D_ * 2) + (size_t)k0 * 2 + kb;
      size_t lo = (size_t)(tx & ~63) * 16;
      gload_lds16((const char*)B0 + go, (char*)Bh + lo);
      gload_lds16((const char*)B0 + DD_ * 2 + go, (char*)Bl + lo);
    }
    __syncthreads();
    short8 a[4], a2[4], b[4], b2[4];
#pragma unroll
    for (int m = 0; m < 4; m++) {
      int rr_ = wm * 64 + m * 16 + (lane & 15);
      int ro = rr_ * 32 + swz(rr_, lane >> 4) * 8;
      a[m] = *(const short8*)(Ah + ro);
      a2[m] = *(const short8*)(Al + ro);
    }
#pragma unroll
    for (int n = 0; n < 4; n++) {
      int rr_ = wn * 64 + n * 16 + (lane & 15);
      int ro = rr_ * 32 + swz(rr_, lane >> 4) * 8;
      b[n] = *(const short8*)(Bh + ro);
      b2[n] = *(const short8*)(Bl + ro);
    }
#pragma unroll
    for (int m = 0; m < 4; m++)
#pragma unroll
      for (int n = 0; n < 4; n++) {
        acc[m][n] = MFMA(a[m], b[n], acc[m][n]);
        acc[m][n] = MFMA(a2[m], b[n], acc[m][n]);
        acc[m][n] = MFMA(a[m], b2[n], acc[m][n]);
      }
    __syncthreads();
  }
  int r0 = rowStart + wm * 64 + ((lane >> 4) << 2);
  int cgl = colStart + wn * 64 + (lane & 15);
#pragma unroll
  for (int m = 0; m < 4; m++)
#pragma unroll
    for (int n = 0; n < 4; n++)
#pragma unroll
      for (int j = 0; j < 4; j++) {
        size_t idx = (size_t)(r0 + m * 16 + j) * D_ + cgl + n * 16;
        float vv = acc[m][n][j];
        if (z == 2) vv = 1.0f / (1.0f + __expf(-vv));
        C[idx] = vv;
      }
}

// ---- Wo split GEMM: K-split z in {0,1}; 4-buffer DOUBLE-BUFFERED counted
// pipeline (grid=256 = 1 block/CU, so 96KB LDS costs no co-residency) ----
__global__ __launch_bounds__(512) void gemm_wo(const short* __restrict__ A,
                                               const short* __restrict__ Bt,
                                               float* __restrict__ P) {
  __shared__ __align__(16) short Ah[2][256 * 32], Al[2][256 * 32];
  __shared__ __align__(16) short Bh[2][128 * 32], Bl[2][128 * 32];
  int tx = threadIdx.x;
  int lane = tx & 63;
  int orig = blockIdx.x + (blockIdx.y << 3) + (blockIdx.z << 7);
  int wgid = (orig & 7) * 32 + (orig >> 3);  // nwg=256, q=32
  int z = wgid >> 7;
  int rem = wgid & 127;
  int colStart = (rem & 7) * 128;
  int rowStart = (rem >> 3) * 256;
  const char* A0 = (const char*)(A + (size_t)rowStart * D_);
  const char* B0 = (const char*)(Bt + (size_t)colStart * D_);
  float* C = P + (size_t)z * MD_;
  int wave = tx >> 6, wm = wave >> 1, wn = wave & 1;
  int kbase = z * (D_ / 2);
  auto stage = [&](int buf, int k0) {  // exactly 6 gload_lds per thread
#pragma unroll
    for (int i = 0; i < 2; i++) {
      int c = i * 512 + tx;
      int row = c >> 2;
      int kb = swz(row, c & 3) * 16;
      size_t go = (size_t)row * (D_ * 2) + (size_t)k0 * 2 + kb;
      size_t lo = (size_t)(i * 512 + (tx & ~63)) * 16;
      gload_lds16(A0 + go, (char*)Ah[buf] + lo);
      gload_lds16(A0 + MD_ * 2 + go, (char*)Al[buf] + lo);
    }
    {
      int row = tx >> 2;
      int kb = swz(row, tx & 3) * 16;
      size_t go = (size_t)row * (D_ * 2) + (size_t)k0 * 2 + kb;
      size_t lo = (size_t)(tx & ~63) * 16;
      gload_lds16(B0 + go, (char*)Bh[buf] + lo);
      gload_lds16(B0 + DD_ * 2 + go, (char*)Bl[buf] + lo);
    }
  };
  f32x4 acc[4][4] = {};
  constexpr int NS = 16;  // (D_/2)/32
  int cur = 0;
  stage(0, kbase);
  for (int s = 0; s < NS; s++) {
    if (s + 1 < NS) {
      stage(cur ^ 1, kbase + (s + 1) * 32);
      asm volatile("s_waitcnt vmcnt(6)" ::: "memory");  // oldest 6 = cur buf
    } else {
      asm volatile("s_waitcnt vmcnt(0)" ::: "memory");
    }
    __builtin_amdgcn_s_barrier();
    short8 a[4], a2[4], b[4], b2[4];
#pragma unroll
    for (int m = 0; m < 4; m++) {
      int rr_ = wm * 64 + m * 16 + (lane & 15);
      int ro = rr_ * 32 + swz(rr_, lane >> 4) * 8;
      a[m] = *(const short8*)(Ah[cur] + ro);
      a2[m] = *(const short8*)(Al[cur] + ro);
    }
#pragma unroll
    for (int n = 0; n < 4; n++) {
      int rr_ = wn * 64 + n * 16 + (lane & 15);
      int ro = rr_ * 32 + swz(rr_, lane >> 4) * 8;
      b[n] = *(const short8*)(Bh[cur] + ro);
      b2[n] = *(const short8*)(Bl[cur] + ro);
    }
    __builtin_amdgcn_s_setprio(1);
#pragma unroll
    for (int m = 0; m < 4; m++)
#pragma unroll
      for (int n = 0; n < 4; n++) {
        acc[m][n] = MFMA(a[m], b[n], acc[m][n]);
        acc[m][n] = MFMA(a2[m], b[n], acc[m][n]);
        acc[m][n] = MFMA(a[m], b2[n], acc[m][n]);
      }
    __builtin_amdgcn_s_setprio(0);
    asm volatile("" ::: "memory");
    __builtin_amdgcn_s_barrier();
    cur ^= 1;
  }
  int r0 = rowStart + wm * 64 + ((lane >> 4) << 2);
  int cgl = colStart + wn * 64 + (lane & 15);
#pragma unroll
  for (int m = 0; m < 4; m++)
#pragma unroll
    for (int n = 0; n < 4; n++)
#pragma unroll
      for (int j = 0; j < 4; j++)
        C[(size_t)(r0 + m * 16 + j) * D_ + cgl + n * 16] = acc[m][n][j];
}

// ---- expert h GEMM: h = relu^2(Ak @ eWkT). 2-phase counted-vmcnt pipeline ----
__global__ __launch_bounds__(512) void gemm_exA(const short* __restrict__ A,
                                                const short* __restrict__ Bt,
                                                short* __restrict__ C,
                                                const int* __restrict__ offs) {
  __shared__ __align__(16) short As[2][256 * 32];
  __shared__ __align__(16) short Bs[2][128 * 32];
  int tx = threadIdx.x;
  int lane = tx & 63;
  int orig = blockIdx.x + (blockIdx.y << 4);
  int wgid = (orig & 7) * 80 + (orig >> 3);  // nwg=640, q=80
  int colStart = (wgid & 15) * 128;
  int rowStart = (wgid >> 4) * 256;
  if (rowStart >= offs[8]) return;
  int e = 0;
  while (e < 7 && rowStart >= offs[e + 1]) e++;
  const char* Ag = (const char*)(A + (size_t)rowStart * D_);
  const char* Bg = (const char*)(Bt + (size_t)e * F_ * D_ + (size_t)colStart * D_);
  int wave = tx >> 6, wm = wave >> 1, wn = wave & 1;
  auto stage = [&](int buf, int s) {  // 3 gload_lds per thread, exactly
    size_t kb2 = (size_t)s << 6;
#pragma unroll
    for (int i = 0; i < 2; i++) {
      int c = i * 512 + tx;
      int row = c >> 2;
      int kb = swz(row, c & 3) * 16;
      gload_lds16(Ag + (size_t)row * (D_ * 2) + kb2 + kb,
                  (char*)As[buf] + (size_t)(i * 512 + (tx & ~63)) * 16);
    }
    {
      int row = tx >> 2;
      int kb = swz(row, tx & 3) * 16;
      gload_lds16(Bg + (size_t)row * (D_ * 2) + kb2 + kb,
                  (char*)Bs[buf] + (size_t)(tx & ~63) * 16);
    }
  };
  f32x4 acc[4][4] = {};
  constexpr int NS = 32;
  int cur = 0;
  stage(0, 0);
  for (int s = 0; s < NS; s++) {
    if (s + 1 < NS) {
      stage(cur ^ 1, s + 1);
      asm volatile("s_waitcnt vmcnt(3)" ::: "memory");  // oldest 3 = cur buf
    } else {
      asm volatile("s_waitcnt vmcnt(0)" ::: "memory");
    }
    __builtin_amdgcn_s_barrier();  // all waves' cur-buf writes landed
    short8 a[4], b[4];
#pragma unroll
    for (int m = 0; m < 4; m++) {
      int rr_ = wm * 64 + m * 16 + (lane & 15);
      a[m] = *(const short8*)(As[cur] + rr_ * 32 + swz(rr_, lane >> 4) * 8);
    }
#pragma unroll
    for (int n = 0; n < 4; n++) {
      int rr_ = wn * 64 + n * 16 + (lane & 15);
      b[n] = *(const short8*)(Bs[cur] + rr_ * 32 + swz(rr_, lane >> 4) * 8);
    }
    __builtin_amdgcn_s_setprio(1);
#pragma unroll
    for (int m = 0; m < 4; m++)
#pragma unroll
      for (int n = 0; n < 4; n++) acc[m][n] = MFMA(a[m], b[n], acc[m][n]);
    __builtin_amdgcn_s_setprio(0);
    asm volatile("" ::: "memory");
    __builtin_amdgcn_s_barrier();  // all reads of cur done before overwrite
    cur ^= 1;
  }
  int r0 = rowStart + wm * 64 + ((lane >> 4) << 2);
  int cgl = colStart + wn * 64 + (lane & 15);
#pragma unroll
  for (int m = 0; m < 4; m++)
#pragma unroll
    for (int n = 0; n < 4; n++)
#pragma unroll
      for (int j = 0; j < 4; j++) {
        size_t idx = (size_t)(r0 + m * 16 + j) * F_ + cgl + n * 16;
        float vv = acc[m][n][j];
        vv = vv > 0.f ? vv * vv : 0.f;
        C[idx] = f2bf(vv);
      }
}

// ---- merged expert GEMMs (2-phase counted-vmcnt): z=0 kvb=h@eWvT; z=1 rrb ----
__global__ __launch_bounds__(512) void gemm_ex2(
    const short* __restrict__ h, const short* __restrict__ eWvT,
    short* __restrict__ kvb, const short* __restrict__ Ar,
    const short* __restrict__ eWrT, short* __restrict__ rrb,
    const int* __restrict__ offs) {
  __shared__ __align__(16) short As[2][256 * 32];
  __shared__ __align__(16) short Bs[2][128 * 32];
  int tx = threadIdx.x;
  int lane = tx & 63;
  int zz = blockIdx.z;
  int orig = blockIdx.x + (blockIdx.y << 3);
  int wgid = (orig & 7) * 40 + (orig >> 3);  // per-slice nwg=320, q=40
  int colStart = (wgid & 7) * 128;
  int rowStart = (wgid >> 3) * 256;
  if (rowStart >= offs[8]) return;
  int e = 0;
  while (e < 7 && rowStart >= offs[e + 1]) e++;
  int K = zz ? D_ : F_;
  const char* Ag = (const char*)((zz ? Ar : h) + (size_t)rowStart * K);
  const char* Bg =
      (const char*)((zz ? eWrT : eWvT) + (size_t)e * D_ * K + (size_t)colStart * K);
  int wave = tx >> 6, wm = wave >> 1, wn = wave & 1;
  const int NS = K / 32;
  auto stage = [&](int buf, int s) {  // 3 gload_lds per thread, exactly
    size_t kb2 = (size_t)s << 6;
#pragma unroll
    for (int i = 0; i < 2; i++) {
      int c = i * 512 + tx;
      int row = c >> 2;
      int kb = swz(row, c & 3) * 16;
      gload_lds16(Ag + (size_t)row * ((size_t)K * 2) + kb2 + kb,
                  (char*)As[buf] + (size_t)(i * 512 + (tx & ~63)) * 16);
    }
    {
      int row = tx >> 2;
      int kb = swz(row, tx & 3) * 16;
      gload_lds16(Bg + (size_t)row * ((size_t)K * 2) + kb2 + kb,
                  (char*)Bs[buf] + (size_t)(tx & ~63) * 16);
    }
  };
  f32x4 acc[4][4] = {};
  int cur = 0;
  stage(0, 0);
  for (int s = 0; s < NS; s++) {
    if (s + 1 < NS) {
      stage(cur ^ 1, s + 1);
      asm volatile("s_waitcnt vmcnt(3)" ::: "memory");
    } else {
      asm volatile("s_waitcnt vmcnt(0)" ::: "memory");
    }
    __builtin_amdgcn_s_barrier();
    short8 a[4], b[4];
#pragma unroll
    for (int m = 0; m < 4; m++) {
      int rr_ = wm * 64 + m * 16 + (lane & 15);
      a[m] = *(const short8*)(As[cur] + rr_ * 32 + swz(rr_, lane >> 4) * 8);
    }
#pragma unroll
    for (int n = 0; n < 4; n++) {
      int rr_ = wn * 64 + n * 16 + (lane & 15);
      b[n] = *(const short8*)(Bs[cur] + rr_ * 32 + swz(rr_, lane >> 4) * 8);
    }
    __builtin_amdgcn_s_setprio(1);
#pragma unroll
    for (int m = 0; m < 4; m++)
#pragma unroll
      for (int n = 0; n < 4; n++) acc[m][n] = MFMA(a[m], b[n], acc[m][n]);
    __builtin_amdgcn_s_setprio(0);
    asm volatile("" ::: "memory");
    __builtin_amdgcn_s_barrier();
    cur ^= 1;
  }
  short* C = zz ? rrb : kvb;
  int r0 = rowStart + wm * 64 + ((lane >> 4) << 2);
  int cgl = colStart + wn * 64 + (lane & 15);
#pragma unroll
  for (int m = 0; m < 4; m++)
#pragma unroll
    for (int n = 0; n < 4; n++)
#pragma unroll
      for (int j = 0; j < 4; j++) {
        size_t idx = (size_t)(r0 + m * 16 + j) * D_ + cgl + n * 16;
        float vv = acc[m][n][j];
        if (zz) vv = 1.0f / (1.0f + __expf(-vv));
        C[idx] = f2bf(vv);
      }
}

// ---------------- WKV chunked scan ----------------
__global__ __launch_bounds__(256) void wkv_chunk_kernel(const float* __restrict__ k,
                                                        const float* __restrict__ v,
                                                        const float* __restrict__ td,
                                                        float* __restrict__ chA,
                                                        float* __restrict__ chB) {
  int d = blockIdx.x * 256 + threadIdx.x;
  int c = blockIdx.y;
  int b = blockIdx.z;
  float w = -__expf(td[d]);
  float dec = __expf(w);
  float A = 0.f, Bb = 0.f;
  size_t base = ((size_t)b * S_ + (size_t)c * L_) * D_ + d;
  for (int i = 0; i < L_; i++) {
    float kt = k[base + (size_t)i * D_];
    float vt = v[base + (size_t)i * D_];
    float ek = __expf(kt);
    A = fmaf(A, dec, ek * vt);
    Bb = fmaf(Bb, dec, ek);
  }
  size_t o = ((size_t)b * NC_ + c) * D_ + d;
  chA[o] = A;
  chB[o] = Bb;
}

__global__ __launch_bounds__(256) void wkv_carry_kernel(const float* __restrict__ chA,
                                                        const float* __restrict__ chB,
                                                        const float* __restrict__ td,
                                                        float* __restrict__ caA,
                                                        float* __restrict__ caB) {
  int d = blockIdx.x * 256 + threadIdx.x;
  int b = blockIdx.y;
  float w = -__expf(td[d]);
  float decL = __expf(w * (float)L_);
  float A = 0.f, Bb = 0.f;
  for (int c = 0; c < NC_; c++) {
    size_t o = ((size_t)b * NC_ + c) * D_ + d;
    caA[o] = A;
    caB[o] = Bb;
    A = fmaf(A, decL, chA[o]);
    Bb = fmaf(Bb, decL, chB[o]);
  }
}

__global__ __launch_bounds__(256) void wkv_out_kernel(
    const float* __restrict__ k, const float* __restrict__ v,
    const float* __restrict__ r, const float* __restrict__ caA,
    const float* __restrict__ caB, const float* __restrict__ td,
    const float* __restrict__ tf, short* __restrict__ rwkv) {
  int d = blockIdx.x * 256 + threadIdx.x;
  int c = blockIdx.y;
  int b = blockIdx.z;
  float w = -__expf(td[d]);
  float dec = __expf(w);
  float eu = __expf(tf[d]);
  size_t co = ((size_t)b * NC_ + c) * D_ + d;
  float A = caA[co], Bb = caB[co];
  size_t base = ((size_t)b * S_ + (size_t)c * L_) * D_ + d;
  for (int i = 0; i < L_; i++) {
    size_t ix = base + (size_t)i * D_;
    float kt = k[ix], vt = v[ix], rt = r[ix];
    float ek = __expf(kt);
    float euk = eu * ek;
    float wkv = (A + euk * vt) / (Bb + euk);
    BfPair p = split2(rt * wkv);
    rwkv[ix] = p.hi;
    rwkv[MD_ + ix] = p.lo;
    A = fmaf(A, dec, ek * vt);
    Bb = fmaf(Bb, dec, ek);
  }
}

// ---------------- MoE gather + channel-mix (build Ak/Ar, bf16) ----------------
__global__ __launch_bounds__(256) void gather_mix_kernel(
    const float* __restrict__ ei, const float* __restrict__ cmk,
    const float* __restrict__ cmr, const int* __restrict__ offs,
    const int* __restrict__ counts, const int* __restrict__ elist,
    short* __restrict__ Ak, short* __restrict__ Ar) {
  int row = blockIdx.x;
  if (row >= offs[8]) return;
  int e = 0;
  while (e < 7 && row >= offs[e + 1]) e++;
  int p = row - offs[e];
  int d = threadIdx.x * 4;
  size_t ro = (size_t)row * D_ + d;
  if (p >= counts[e]) {
    s16x4 z = {0, 0, 0, 0};
    *(s16x4*)(Ak + ro) = z;
    *(s16x4*)(Ar + ro) = z;
    return;
  }
  int t = elist[row];
  int s = t & (S_ - 1);
  f32x4 cur = *(const f32x4*)(ei + (size_t)t * D_ + d);
  f32x4 prev = {0.f, 0.f, 0.f, 0.f};
  if (s > 0) prev = *(const f32x4*)(ei + (size_t)(t - 1) * D_ + d);
  f32x4 mk = *(const f32x4*)(cmk + (size_t)e * D_ + d);
  f32x4 mr = *(const f32x4*)(cmr + (size_t)e * D_ + d);
  s16x4 ok, orr;
#pragma unroll
  for (int j = 0; j < 4; j++) {
    ok[j] = f2bf(cur[j] * mk[j] + prev[j] * (1.f - mk[j]));
    orr[j] = f2bf(cur[j] * mr[j] + prev[j] * (1.f - mr[j]));
  }
  *(s16x4*)(Ak + ro) = ok;
  *(s16x4*)(Ar + ro) = orr;
}

// ---------------- final: out = xout + sum_j w_j * rr * kv ----------------
__global__ __launch_bounds__(256) void final_kernel(
    const float* __restrict__ xout, const short* __restrict__ rrb,
    const short* __restrict__ kvb, const int* __restrict__ slots,
    const float* __restrict__ wts2, float* __restrict__ out) {
  size_t i4 = (size_t)blockIdx.x * 256 + threadIdx.x;
  size_t el = i4 * 4;
  int t = (int)(el >> 10);
  int d = (int)(el & (D_ - 1));
  int s0 = slots[t * 2], s1 = slots[t * 2 + 1];
  float w0 = wts2[t * 2], w1 = wts2[t * 2 + 1];
  f32x4 xo = *(const f32x4*)(xout + el);
  s16x4 r0 = *(const s16x4*)(rrb + (size_t)s0 * D_ + d);
  s16x4 k0 = *(const s16x4*)(kvb + (size_t)s0 * D_ + d);
  s16x4 r1 = *(const s16x4*)(rrb + (size_t)s1 * D_ + d);
  s16x4 k1 = *(const s16x4*)(kvb + (size_t)s1 * D_ + d);
  f32x4 o;
#pragma unroll
  for (int j = 0; j < 4; j++)
    o[j] = xo[j] + w0 * bf2f(r0[j]) * bf2f(k0[j]) + w1 * bf2f(r1[j]) * bf2f(k1[j]);
  *(f32x4*)(out + el) = o;
}

// ============================================================================
extern "C" void kernel_launch(void* const* d_in, const int* in_sizes, int n_in,
                              void* d_out, int out_size, void* d_ws, size_t ws_size,
                              hipStream_t stream) {
  (void)in_sizes; (void)n_in; (void)out_size; (void)ws_size;
  const float* x = (const float*)d_in[0];
  const float* ln1g = (const float*)d_in[1];
  const float* ln1b = (const float*)d_in[2];
  const float* ln2g = (const float*)d_in[3];
  const float* ln2b = (const float*)d_in[4];
  const float* muk = (const float*)d_in[5];
  const float* muv = (const float*)d_in[6];
  const float* mur = (const float*)d_in[7];
  const float* tdec = (const float*)d_in[8];
  const float* tfirst = (const float*)d_in[9];
  const float* Wk = (const float*)d_in[10];
  const float* Wv = (const float*)d_in[11];
  const float* Wr = (const float*)d_in[12];
  const float* Wo = (const float*)d_in[13];
  const float* rw = (const float*)d_in[14];
  const float* cmk = (const float*)d_in[15];
  const float* cmr = (const float*)d_in[16];
  const float* eWk = (const float*)d_in[17];
  const float* eWv = (const float*)d_in[18];
  const float* eWr = (const float*)d_in[19];
  float* out = (float*)d_out;

  char* w = (char*)d_ws;
  size_t off = 0;
  auto alloc = [&](size_t bytes) {
    size_t o = off;
    off = (off + bytes + 255) & ~(size_t)255;
    return o;
  };
  const size_t szDD2x2 = DD_ * 2 * 2;
  size_t o_WT = alloc(4 * szDD2x2);
  size_t o_WkT = o_WT, o_WoT = o_WT + 3 * szDD2x2;
  size_t o_eWkT = alloc((size_t)E_ * D_ * F_ * 2);
  size_t o_eWvT = alloc((size_t)E_ * F_ * D_ * 2);
  size_t o_eWrT = alloc((size_t)E_ * D_ * D_ * 2);
  size_t o_xout = alloc(MD_ * 4);
  size_t o_ei = alloc(MD_ * 4);
  size_t o_counts = alloc(64);
  size_t o_offs = alloc(64);
  size_t o_idx2 = alloc((size_t)M_ * 2 * 4);
  size_t o_wts2 = alloc((size_t)M_ * 2 * 4);
  size_t o_pos2 = alloc((size_t)M_ * 2 * 4);
  size_t o_blockcnt = alloc((size_t)HB_ * 8 * 4);
  size_t o_gbase = alloc((size_t)HB_ * 8 * 4);
  size_t o_elist = alloc((size_t)PC_ * 4);
  size_t o_slots = alloc((size_t)M_ * 2 * 4);
  size_t poolBase = off;
  size_t off1 = poolBase;
  auto alloc1 = [&](size_t bytes) {
    size_t o = off1;
    off1 = (off1 + bytes + 255) & ~(size_t)255;
    return o;
  };
  size_t o_rwkv = alloc1(MD_ * 2 * 2);
  size_t o_xk = alloc1(MD_ * 2 * 2);
  size_t o_xv = alloc1(MD_ * 2 * 2);
  size_t o_xr = alloc1(MD_ * 2 * 2);
  size_t o_k = alloc1(MD_ * 4);
  size_t o_v = alloc1(MD_ * 4);
  size_t o_r = alloc1(MD_ * 4);
  size_t o_chA = alloc1((size_t)B_ * NC_ * D_ * 4);
  size_t o_chB = alloc1((size_t)B_ * NC_ * D_ * 4);
  size_t o_caA = alloc1((size_t)B_ * NC_ * D_ * 4);
  size_t o_caB = alloc1((size_t)B_ * NC_ * D_ * 4);
  size_t o_P = o_k;  // alias: k/v dead after wkv_out
  size_t off2 = poolBase;
  auto alloc2 = [&](size_t bytes) {
    size_t o = off2;
    off2 = (off2 + bytes + 255) & ~(size_t)255;
    return o;
  };
  size_t o_Ak = alloc2((size_t)PC_ * D_ * 2);
  size_t o_Ar = alloc2((size_t)PC_ * D_ * 2);
  size_t o_h = alloc2((size_t)PC_ * F_ * 2);
  size_t o_kvb = alloc2((size_t)PC_ * D_ * 2);
  size_t o_rrb = alloc2((size_t)PC_ * D_ * 2);

#define WP(T, o) ((T*)(w + (o)))

  transpose_cvt4<<<dim3(32, 32, 4), 256, 0, stream>>>(Wk, Wv, Wr, Wo,
                                                      WP(short, o_WkT));
  transpose_cvt<0><<<dim3(F_ / 32, D_ / 32, E_), 256, 0, stream>>>(eWk, WP(short, o_eWkT), D_, F_);
  transpose_cvt<0><<<dim3(D_ / 32, F_ / 32, E_), 256, 0, stream>>>(eWv, WP(short, o_eWvT), F_, D_);
  transpose_cvt<0><<<dim3(D_ / 32, D_ / 32, E_), 256, 0, stream>>>(eWr, WP(short, o_eWrT), D_, D_);

  lnmix_kernel<<<M_, 256, 0, stream>>>(x, ln1g, ln1b, muk, muv, mur,
                                       WP(short, o_xk), WP(short, o_xv),
                                       WP(short, o_xr));

  gemm_kvr<<<dim3(8, 16, 3), 512, 0, stream>>>(WP(short, o_xk), WP(short, o_WkT),
                                               WP(float, o_k));

  wkv_chunk_kernel<<<dim3(D_ / 256, NC_, B_), 256, 0, stream>>>(
      WP(float, o_k), WP(float, o_v), tdec, WP(float, o_chA), WP(float, o_chB));
  wkv_carry_kernel<<<dim3(D_ / 256, B_), 256, 0, stream>>>(
      WP(float, o_chA), WP(float, o_chB), tdec, WP(float, o_caA), WP(float, o_caB));
  wkv_out_kernel<<<dim3(D_ / 256, NC_, B_), 256, 0, stream>>>(
      WP(float, o_k), WP(float, o_v), WP(float, o_r), WP(float, o_caA),
      WP(float, o_caB), tdec, tfirst, WP(short, o_rwkv));

  gemm_wo<<<dim3(8, 16, 2), 512, 0, stream>>>(WP(short, o_rwkv), WP(short, o_WoT),
                                              WP(float, o_P));
  ln2_router<<<M_, 256, 0, stream>>>(x, WP(float, o_P), ln2g, ln2b, rw,
                                     WP(float, o_xout), WP(float, o_ei),
                                     WP(int, o_idx2), WP(float, o_wts2));

  hist_kernel<<<HB_, 512, 0, stream>>>(WP(int, o_idx2), WP(int, o_pos2),
                                       WP(int, o_blockcnt));
  scan_kernel<<<1, 128, 0, stream>>>(WP(int, o_blockcnt), WP(int, o_offs),
                                     WP(int, o_counts), WP(int, o_gbase));
  slot_kernel<<<(2 * M_) / 256, 256, 0, stream>>>(WP(int, o_idx2), WP(int, o_pos2),
                                                  WP(int, o_gbase), WP(int, o_elist),
                                                  WP(int, o_slots));
  gather_mix_kernel<<<PC_, 256, 0, stream>>>(WP(float, o_ei), cmk, cmr, WP(int, o_offs),
                                             WP(int, o_counts), WP(int, o_elist),
                                             WP(short, o_Ak), WP(short, o_Ar));

  gemm_exA<<<dim3(16, 40), 512, 0, stream>>>(WP(short, o_Ak), WP(short, o_eWkT),
                                             WP(short, o_h), WP(int, o_offs));
  gemm_ex2<<<dim3(8, 40, 2), 512, 0, stream>>>(
      WP(short, o_h), WP(short, o_eWvT), WP(short, o_kvb), WP(short, o_Ar),
      WP(short, o_eWrT), WP(short, o_rrb), WP(int, o_offs));

  final_kernel<<<M_ * D_ / 4 / 256, 256, 0, stream>>>(
      WP(float, o_xout), WP(short, o_rrb), WP(short, o_kvb), WP(int, o_slots),
      WP(float, o_wts2), out);
#undef WP
}